// Round 1
// baseline (3699.438 us; speedup 1.0000x reference)
//
#include <hip/hip_runtime.h>

// ---------------------------------------------------------------------------
// PerceiverResampler forward, MI355X gfx950.
// Residual stream (lat) lives in d_out (f32). bf16 MFMA GEMMs, f32 accum.
// Workspace requirement: ~230 MB.
// ---------------------------------------------------------------------------

typedef __attribute__((ext_vector_type(4))) float f32x4;
typedef __attribute__((ext_vector_type(8))) __bf16 bf16x8;
typedef __attribute__((ext_vector_type(4))) __bf16 bf16x4;

#define BATCH 32
#define SEQL  512
#define DIM   1024
#define HEADS 16
#define DH    64
#define LTOT  68          // 4 mean-pool latents + 64 learned
#define KEYS  580         // SEQL + LTOT
#define HID   4096
#define LN_EPS 1e-5f

__device__ __forceinline__ float bf2f(__bf16 v) { return (float)v; }
__device__ __forceinline__ __bf16 f2bf(float v) { return (__bf16)v; }

// ---------------- block-wide 2-value sum reduction (256 threads) ------------
__device__ __forceinline__ void block_reduce2(float& a, float& b, float* red) {
#pragma unroll
    for (int m = 32; m > 0; m >>= 1) {
        a += __shfl_xor(a, m, 64);
        b += __shfl_xor(b, m, 64);
    }
    int wid = threadIdx.x >> 6, lane = threadIdx.x & 63;
    __syncthreads();                    // protect red[] reuse across calls
    if (lane == 0) { red[wid] = a; red[4 + wid] = b; }
    __syncthreads();
    a = red[0] + red[1] + red[2] + red[3];
    b = red[4] + red[5] + red[6] + red[7];
}

// ---------------- x_pos = bf16(x + pos_emb) --------------------------------
__global__ __launch_bounds__(256) void add_pos(const float* __restrict__ x,
                                               const float* __restrict__ pos,
                                               __bf16* __restrict__ xp) {
    const int total4 = (BATCH * SEQL * DIM) / 4;   // 4,194,304
    const int pos4m = (SEQL * DIM) / 4 - 1;        // 131071 (pow2-1)
    for (int i = blockIdx.x * 256 + threadIdx.x; i < total4; i += gridDim.x * 256) {
        f32x4 xv = ((const f32x4*)x)[i];
        f32x4 pv = ((const f32x4*)pos)[i & pos4m];
        bf16x4 o;
#pragma unroll
        for (int j = 0; j < 4; ++j) o[j] = f2bf(xv[j] + pv[j]);
        ((bf16x4*)xp)[i] = o;
    }
}

// ---------------- pooled[b][d] = mean_s x[b,s,d] ---------------------------
__global__ __launch_bounds__(256) void pool_mean(const float* __restrict__ x,
                                                 float* __restrict__ pooled) {
    int b = blockIdx.x >> 2;
    int d = ((blockIdx.x & 3) << 8) + threadIdx.x;
    const float* p = x + (size_t)b * SEQL * DIM + d;
    float s = 0.f;
    for (int ss = 0; ss < SEQL; ++ss) s += p[(size_t)ss * DIM];
    pooled[b * DIM + d] = s * (1.f / SEQL);
}

// ---------------- lat rows 4..67 = latents ---------------------------------
__global__ __launch_bounds__(256) void lat_fill(const float* __restrict__ latents,
                                                float* __restrict__ lat) {
    int i = blockIdx.x * 256 + threadIdx.x;        // < 524288
    int b = i >> 14;
    int rem = i & 16383;
    int r = rem >> 8, d4 = rem & 255;
    ((f32x4*)lat)[(size_t)(b * LTOT + 4 + r) * 256 + d4] = ((const f32x4*)latents)[rem];
}

// ---------------- row LayerNorm -> bf16 ------------------------------------
// STD: (x-mean)*rstd*w + b   ;  !STD (custom): (x-mean)*rstd*w
template <typename Tin, bool STD, int COLS>
__global__ __launch_bounds__(256) void ln_rows(const Tin* __restrict__ in,
                                               __bf16* __restrict__ out,
                                               const float* __restrict__ w,
                                               const float* __restrict__ bb) {
    __shared__ float red[8];
    constexpr int NPT = COLS / 256;
    size_t base = (size_t)blockIdx.x * COLS;
    int t = threadIdx.x;
    float xv[NPT];
    float s = 0.f, s2 = 0.f;
#pragma unroll
    for (int k = 0; k < NPT; ++k) {
        float v = (float)in[base + t + (k << 8)];
        xv[k] = v; s += v; s2 += v * v;
    }
    block_reduce2(s, s2, red);
    float mean = s * (1.f / COLS);
    float var = s2 * (1.f / COLS) - mean * mean;
    float rstd = rsqrtf(var + LN_EPS);
#pragma unroll
    for (int k = 0; k < NPT; ++k) {
        int c = t + (k << 8);
        float y = (xv[k] - mean) * rstd * w[c];
        if (STD) y += bb[c];
        out[base + c] = f2bf(y);
    }
}

// ------- fused: lat = std_ln(gin)*w+b + lat ; ffin = custom_ln(lat)*g1 -----
__global__ __launch_bounds__(256) void wout_ln_res(const float* __restrict__ gin,
                                                   float* __restrict__ lat,
                                                   __bf16* __restrict__ ffin,
                                                   const float* __restrict__ w,
                                                   const float* __restrict__ b,
                                                   const float* __restrict__ g1) {
    __shared__ float red[8];
    size_t base = (size_t)blockIdx.x * DIM;
    int t = threadIdx.x;
    float xv[4];
    float s = 0.f, s2 = 0.f;
#pragma unroll
    for (int k = 0; k < 4; ++k) {
        float v = gin[base + t + (k << 8)];
        xv[k] = v; s += v; s2 += v * v;
    }
    block_reduce2(s, s2, red);
    float mean = s * (1.f / DIM);
    float var = s2 * (1.f / DIM) - mean * mean;
    float rstd = rsqrtf(var + LN_EPS);
    float yv[4];
    s = 0.f; s2 = 0.f;
#pragma unroll
    for (int k = 0; k < 4; ++k) {
        int c = t + (k << 8);
        float y = (xv[k] - mean) * rstd * w[c] + b[c] + lat[base + c];
        yv[k] = y; s += y; s2 += y * y;
        lat[base + c] = y;
    }
    block_reduce2(s, s2, red);
    float mean2 = s * (1.f / DIM);
    float var2 = s2 * (1.f / DIM) - mean2 * mean2;
    float rstd2 = rsqrtf(var2 + LN_EPS);
#pragma unroll
    for (int k = 0; k < 4; ++k) {
        int c = t + (k << 8);
        ffin[base + c] = f2bf((yv[k] - mean2) * rstd2 * g1[c]);
    }
}

// ---------------- transpose + cast: in[K,N] f32 -> out[N,K] bf16 -----------
__global__ __launch_bounds__(256) void transpose_cast(const float* __restrict__ in,
                                                      __bf16* __restrict__ out,
                                                      int K, int N) {
    __shared__ float tile[32][33];
    int n0 = blockIdx.x * 32, k0 = blockIdx.y * 32;
    int tx = threadIdx.x & 31, ty = threadIdx.x >> 5;
#pragma unroll
    for (int p = 0; p < 4; ++p) {
        int kk = ty + p * 8;
        tile[kk][tx] = in[(size_t)(k0 + kk) * N + n0 + tx];
    }
    __syncthreads();
#pragma unroll
    for (int p = 0; p < 4; ++p) {
        int nn = ty + p * 8;
        out[(size_t)(n0 + nn) * K + k0 + tx] = f2bf(tile[tx][nn]);
    }
}

// ---------------- bf16 MFMA GEMM: C = A[M,K] @ Bt[N,K]^T -------------------
// 128x128 tile, BK=64, 4 waves (2x2), 16x16x32 MFMA, XOR-swizzled LDS.
// EPI: 0=f32, 1=bf16, 2=bf16*scale, 3=gelu->f32, 4=f32 + Cres
template <int EPI>
__global__ __launch_bounds__(256) void gemm_bf16(
    const __bf16* __restrict__ A, const __bf16* __restrict__ Bt,
    void* __restrict__ Cout, const float* __restrict__ bias,
    const float* __restrict__ Cres,
    int M, int N, int K, int batch_rows, long long batch_stride, int ldc,
    float scale) {
    __shared__ __bf16 As[128][64];
    __shared__ __bf16 Bs[128][64];
    const int t = threadIdx.x;
    const int m0 = blockIdx.y * 128, n0 = blockIdx.x * 128;
    const int wid = t >> 6, lane = t & 63;
    const int wr = wid >> 1, wc = wid & 1;
    const int lrow = lane & 15, lk = (lane >> 4) << 3;
    f32x4 acc[4][4] = {};
    const int srow = t >> 3;          // staging row (0..31), +32 per it
    const int sc8 = t & 7;            // staging 8-elem chunk
    const bf16x8 zero8 = {};

    for (int kt = 0; kt < K; kt += 64) {
#pragma unroll
        for (int it = 0; it < 4; ++it) {
            int r = srow + it * 32;
            int col = ((sc8 ^ (r & 7)) << 3);
            bf16x8 va = zero8;
            int gm = m0 + r;
            if (gm < M) va = *(const bf16x8*)(A + (size_t)gm * K + kt + (sc8 << 3));
            *(bf16x8*)(&As[r][col]) = va;
            bf16x8 vb = zero8;
            int gn = n0 + r;
            if (gn < N) vb = *(const bf16x8*)(Bt + (size_t)gn * K + kt + (sc8 << 3));
            *(bf16x8*)(&Bs[r][col]) = vb;
        }
        __syncthreads();
#pragma unroll
        for (int kc = 0; kc < 2; ++kc) {
            const int ck = (kc << 2) + (lane >> 4);
            bf16x8 af[4], bfr[4];
#pragma unroll
            for (int f = 0; f < 4; ++f) {
                int ra = wr * 64 + f * 16 + lrow;
                af[f] = *(const bf16x8*)(&As[ra][(ck ^ (ra & 7)) << 3]);
                int rb = wc * 64 + f * 16 + lrow;
                bfr[f] = *(const bf16x8*)(&Bs[rb][(ck ^ (rb & 7)) << 3]);
            }
#pragma unroll
            for (int fm = 0; fm < 4; ++fm)
#pragma unroll
                for (int fn = 0; fn < 4; ++fn)
                    acc[fm][fn] = __builtin_amdgcn_mfma_f32_16x16x32_bf16(
                        af[fm], bfr[fn], acc[fm][fn], 0, 0, 0);
        }
        __syncthreads();
    }
    // epilogue: C/D layout col=lane&15, row=(lane>>4)*4+j  [m89]
    const int rbase = (lane >> 4) << 2;
    const int cofs = lane & 15;
#pragma unroll
    for (int fm = 0; fm < 4; ++fm) {
#pragma unroll
        for (int j = 0; j < 4; ++j) {
            int m = m0 + wr * 64 + fm * 16 + rbase + j;
            if (m >= M) continue;
            long long roff = (long long)(m / batch_rows) * batch_stride +
                             (long long)(m % batch_rows) * ldc;
#pragma unroll
            for (int fn = 0; fn < 4; ++fn) {
                int n = n0 + wc * 64 + fn * 16 + cofs;
                if (n >= N) continue;
                float v = acc[fm][fn][j];
                if (bias) v += bias[n];
                if (EPI == 0) ((float*)Cout)[roff + n] = v;
                else if (EPI == 1) ((__bf16*)Cout)[roff + n] = f2bf(v);
                else if (EPI == 2) ((__bf16*)Cout)[roff + n] = f2bf(v * scale);
                else if (EPI == 3) ((float*)Cout)[roff + n] =
                    0.5f * v * (1.0f + erff(v * 0.70710678118654752f));
                else ((float*)Cout)[roff + n] = v + Cres[roff + n];
            }
        }
    }
}

// ---------------- fused flash attention per (b,h) --------------------------
// q: [B, 68, 1024] bf16 (pre-scaled); kv: [B, 580, 2048] bf16; out bf16.
__global__ __launch_bounds__(256) void attn_kernel(const __bf16* __restrict__ q,
                                                   const __bf16* __restrict__ kv,
                                                   __bf16* __restrict__ out) {
    __shared__ float qs_f[LTOT][64];    // 17408 B
    __shared__ __bf16 ks[64][64];       // 8192 B (chunk-swizzled)
    __shared__ float vs_f[64][64];      // 16384 B
    __shared__ float ps[LTOT][65];      // 17680 B (padded)
    __shared__ float scale_s[LTOT], l_s[LTOT];

    const int t = threadIdx.x;
    const int b = blockIdx.x >> 4;
    const int h = blockIdx.x & 15;

    const __bf16* qbase = q + (size_t)b * LTOT * DIM + h * DH;
    for (int cc = t; cc < LTOT * 8; cc += 256) {
        int r = cc >> 3, c8 = cc & 7;
        bf16x8 v = *(const bf16x8*)(qbase + (size_t)r * DIM + (c8 << 3));
#pragma unroll
        for (int e = 0; e < 8; ++e) qs_f[r][(c8 << 3) + e] = bf2f(v[e]);
    }

    float av[2][16];
#pragma unroll
    for (int s2 = 0; s2 < 2; ++s2)
#pragma unroll
        for (int e = 0; e < 16; ++e) av[s2][e] = 0.f;
    float m_r = -1e30f, l_r = 0.f;

    const __bf16* kbase = kv + (size_t)b * KEYS * 2048 + h * DH;
    const __bf16* vbase = kbase + 1024;

    for (int jt = 0; jt < 10; ++jt) {
        const int j0 = jt << 6;
        __syncthreads();
#pragma unroll
        for (int p = 0; p < 2; ++p) {
            int cc = t + (p << 8);
            int jj = cc >> 3, c8 = cc & 7;
            int j = j0 + jj;
            bf16x8 kk = {}, vv = {};
            if (j < KEYS) {
                kk = *(const bf16x8*)(kbase + (size_t)j * 2048 + (c8 << 3));
                vv = *(const bf16x8*)(vbase + (size_t)j * 2048 + (c8 << 3));
            }
            *(bf16x8*)(&ks[jj][(c8 ^ (jj & 7)) << 3]) = kk;
#pragma unroll
            for (int e = 0; e < 8; ++e) vs_f[jj][(c8 << 3) + e] = bf2f(vv[e]);
        }
        __syncthreads();
        for (int idx = t; idx < LTOT * 64; idx += 256) {
            int r = idx >> 6, jj = idx & 63;
            float s = 0.f;
#pragma unroll
            for (int c8 = 0; c8 < 8; ++c8) {
                const f32x4* qp = (const f32x4*)(&qs_f[r][c8 << 3]);
                f32x4 q0 = qp[0], q1 = qp[1];
                bf16x8 kk = *(const bf16x8*)(&ks[jj][(c8 ^ (jj & 7)) << 3]);
#pragma unroll
                for (int e = 0; e < 4; ++e) {
                    s += q0[e] * bf2f(kk[e]);
                    s += q1[e] * bf2f(kk[4 + e]);
                }
            }
            ps[r][jj] = (j0 + jj < KEYS) ? s : -3.0e38f;
        }
        __syncthreads();
        if (t < LTOT) {
            float tm = -3.0e38f;
            for (int jj = 0; jj < 64; ++jj) tm = fmaxf(tm, ps[t][jj]);
            float mnew = fmaxf(m_r, tm);
            float sc = __expf(m_r - mnew);
            float sum = 0.f;
            for (int jj = 0; jj < 64; ++jj) {
                float pv = __expf(ps[t][jj] - mnew);
                ps[t][jj] = pv;
                sum += pv;
            }
            l_r = l_r * sc + sum;
            m_r = mnew;
            scale_s[t] = sc;
        }
        __syncthreads();
#pragma unroll
        for (int s2 = 0; s2 < 2; ++s2) {
            int slot = t + (s2 << 8);
            if (slot < LTOT * 4) {
                int r = slot >> 2, d0 = (slot & 3) << 4;
                float sc = scale_s[r];
#pragma unroll
                for (int e = 0; e < 16; ++e) av[s2][e] *= sc;
                for (int jj = 0; jj < 64; ++jj) {
                    float p = ps[r][jj];
                    const f32x4* vp = (const f32x4*)(&vs_f[jj][d0]);
                    f32x4 v0 = vp[0], v1 = vp[1], v2 = vp[2], v3 = vp[3];
#pragma unroll
                    for (int e = 0; e < 4; ++e) {
                        av[s2][e] += p * v0[e];
                        av[s2][4 + e] += p * v1[e];
                        av[s2][8 + e] += p * v2[e];
                        av[s2][12 + e] += p * v3[e];
                    }
                }
            }
        }
    }
    if (t < LTOT) l_s[t] = l_r;
    __syncthreads();
    __bf16* obase = out + (size_t)b * LTOT * DIM + h * DH;
#pragma unroll
    for (int s2 = 0; s2 < 2; ++s2) {
        int slot = t + (s2 << 8);
        if (slot < LTOT * 4) {
            int r = slot >> 2, d0 = (slot & 3) << 4;
            float inv = 1.f / l_s[r];
#pragma unroll
            for (int e = 0; e < 16; ++e)
                obase[(size_t)r * DIM + d0 + e] = f2bf(av[s2][e] * inv);
        }
    }
}

// ---------------------------------------------------------------------------
static void launch_gemm(int epi, const __bf16* A, const __bf16* Bt, void* C,
                        const float* bias, const float* Cres, int M, int N, int K,
                        int br, long long bs, int ldc, float scale,
                        hipStream_t stream) {
    dim3 g(N / 128, (M + 127) / 128), blk(256);
    switch (epi) {
        case 0: gemm_bf16<0><<<g, blk, 0, stream>>>(A, Bt, C, bias, Cres, M, N, K, br, bs, ldc, scale); break;
        case 1: gemm_bf16<1><<<g, blk, 0, stream>>>(A, Bt, C, bias, Cres, M, N, K, br, bs, ldc, scale); break;
        case 2: gemm_bf16<2><<<g, blk, 0, stream>>>(A, Bt, C, bias, Cres, M, N, K, br, bs, ldc, scale); break;
        case 3: gemm_bf16<3><<<g, blk, 0, stream>>>(A, Bt, C, bias, Cres, M, N, K, br, bs, ldc, scale); break;
        default: gemm_bf16<4><<<g, blk, 0, stream>>>(A, Bt, C, bias, Cres, M, N, K, br, bs, ldc, scale); break;
    }
}

extern "C" void kernel_launch(void* const* d_in, const int* in_sizes, int n_in,
                              void* d_out, int out_size, void* d_ws, size_t ws_size,
                              hipStream_t stream) {
    (void)in_sizes; (void)n_in; (void)out_size; (void)ws_size;
    const float* x          = (const float*)d_in[0];
    // d_in[1] mask: all-true, unused
    const float* pos_emb    = (const float*)d_in[2];
    const float* latents    = (const float*)d_in[3];
    const float* mp_ln_g    = (const float*)d_in[4];
    const float* mp_w       = (const float*)d_in[5];
    const float* mp_b       = (const float*)d_in[6];
    const float* attn_norm_w= (const float*)d_in[7];
    const float* attn_norm_b= (const float*)d_in[8];
    const float* attn_lat_w = (const float*)d_in[9];
    const float* attn_lat_b = (const float*)d_in[10];
    const float* Wq         = (const float*)d_in[11];
    const float* Wkv        = (const float*)d_in[12];
    const float* Wout       = (const float*)d_in[13];
    const float* out_ln_w   = (const float*)d_in[14];
    const float* out_ln_b   = (const float*)d_in[15];
    const float* ff_ln1_g   = (const float*)d_in[16];
    const float* ff_w1      = (const float*)d_in[17];
    const float* ff_ln2_g   = (const float*)d_in[18];
    const float* ff_w2      = (const float*)d_in[19];

    float* lat = (float*)d_out;                    // residual stream, f32

    char* ws = (char*)d_ws;
    size_t off = 0;
    auto take = [&](size_t bytes) -> char* {
        char* p = ws + off;
        off += (bytes + 255) & ~(size_t)255;
        return p;
    };
    __bf16* xpos = (__bf16*)take(2ULL * BATCH * SEQL * DIM);
    __bf16* xn   = (__bf16*)take(2ULL * BATCH * SEQL * DIM);
    __bf16* lnl  = (__bf16*)take(2ULL * BATCH * LTOT * DIM);
    __bf16* ffin = (__bf16*)take(2ULL * BATCH * LTOT * DIM);
    __bf16* qb   = (__bf16*)take(2ULL * BATCH * LTOT * DIM);
    __bf16* ao   = (__bf16*)take(2ULL * BATCH * LTOT * DIM);
    __bf16* kvb  = (__bf16*)take(2ULL * BATCH * KEYS * 2048);
    float*  gout = (float*)take(4ULL * BATCH * LTOT * HID);
    __bf16* h2   = (__bf16*)take(2ULL * BATCH * LTOT * HID);
    __bf16* wT   = (__bf16*)take(2ULL * 12 * 1024 * 1024);
    float*  pooled = (float*)take(4ULL * BATCH * DIM);
    __bf16* mpin = (__bf16*)take(2ULL * BATCH * DIM);

    __bf16* wqT   = wT;                    // [1024,1024]
    __bf16* wkvT  = wT + 1 * 1024 * 1024;  // [2048,1024]
    __bf16* woutT = wT + 3 * 1024 * 1024;  // [1024,1024]
    __bf16* f1T   = wT + 4 * 1024 * 1024;  // [4096,1024]
    __bf16* f2T   = wT + 8 * 1024 * 1024;  // [1024,4096]
    __bf16* mpwT  = wT;                    // [4096,1024], used before layers

    // ---- prologue -----------------------------------------------------
    add_pos<<<4096, 256, 0, stream>>>(x, pos_emb, xpos);
    pool_mean<<<128, 256, 0, stream>>>(x, pooled);
    ln_rows<float, false, DIM><<<BATCH, 256, 0, stream>>>(pooled, mpin, mp_ln_g, nullptr);
    transpose_cast<<<dim3(4096 / 32, 1024 / 32), 256, 0, stream>>>(mp_w, mpwT, 1024, 4096);
    // mp_lat -> lat rows 0..3 per batch (ldc = 68*1024 puts n in [0,4096) there)
    launch_gemm(0, mpin, mpwT, lat, mp_b, nullptr, BATCH, 4096, 1024,
                BATCH, 0, LTOT * DIM, 1.f, stream);
    lat_fill<<<2048, 256, 0, stream>>>(latents, lat);

    // ---- layers -------------------------------------------------------
    for (int i = 0; i < 4; ++i) {
        transpose_cast<<<dim3(32, 32), 256, 0, stream>>>(Wq + (size_t)i * 1024 * 1024, wqT, 1024, 1024);
        transpose_cast<<<dim3(64, 32), 256, 0, stream>>>(Wkv + (size_t)i * 1024 * 2048, wkvT, 1024, 2048);
        transpose_cast<<<dim3(32, 32), 256, 0, stream>>>(Wout + (size_t)i * 1024 * 1024, woutT, 1024, 1024);
        transpose_cast<<<dim3(128, 32), 256, 0, stream>>>(ff_w1 + (size_t)i * 1024 * 4096, f1T, 1024, 4096);
        transpose_cast<<<dim3(32, 128), 256, 0, stream>>>(ff_w2 + (size_t)i * 4096 * 1024, f2T, 4096, 1024);

        ln_rows<__bf16, true, DIM><<<BATCH * SEQL, 256, 0, stream>>>(
            xpos, xn, attn_norm_w + i * DIM, attn_norm_b + i * DIM);
        ln_rows<float, true, DIM><<<BATCH * LTOT, 256, 0, stream>>>(
            lat, lnl, attn_lat_w + i * DIM, attn_lat_b + i * DIM);

        // q = (lnl @ Wq) * 0.125  -> bf16
        launch_gemm(2, lnl, wqT, qb, nullptr, nullptr, BATCH * LTOT, 1024, 1024,
                    BATCH * LTOT, 0, 1024, 0.125f, stream);
        // kv rows 0..511 per batch from xn
        launch_gemm(1, xn, wkvT, kvb, nullptr, nullptr, BATCH * SEQL, 2048, 1024,
                    SEQL, (long long)KEYS * 2048, 2048, 1.f, stream);
        // kv rows 512..579 per batch from lnl
        launch_gemm(1, lnl, wkvT, kvb + 512 * 2048, nullptr, nullptr, BATCH * LTOT, 2048, 1024,
                    LTOT, (long long)KEYS * 2048, 2048, 1.f, stream);

        attn_kernel<<<BATCH * HEADS, 256, 0, stream>>>(qb, kvb, ao);

        launch_gemm(0, ao, woutT, gout, nullptr, nullptr, BATCH * LTOT, 1024, 1024,
                    BATCH * LTOT, 0, 1024, 1.f, stream);
        wout_ln_res<<<BATCH * LTOT, 256, 0, stream>>>(
            gout, lat, ffin, out_ln_w + i * DIM, out_ln_b + i * DIM, ff_ln1_g + i * DIM);

        launch_gemm(3, ffin, f1T, gout, nullptr, nullptr, BATCH * LTOT, HID, 1024,
                    BATCH * LTOT, 0, HID, 1.f, stream);
        ln_rows<float, false, HID><<<BATCH * LTOT, 256, 0, stream>>>(
            gout, h2, ff_ln2_g + i * HID, nullptr);
        launch_gemm(4, h2, f2T, lat, nullptr, lat, BATCH * LTOT, 1024, HID,
                    BATCH * LTOT, 0, 1024, 1.f, stream);
    }
}

// Round 2
// 2648.786 us; speedup vs baseline: 1.3967x; 1.3967x over previous
//
#include <hip/hip_runtime.h>

// ---------------------------------------------------------------------------
// PerceiverResampler forward, MI355X gfx950.
// Residual stream (lat) lives in d_out (f32). bf16 MFMA GEMMs, f32 accum.
// R2: global_load_lds width-16 staging (linear LDS dest + pre-swizzled global
// source, m97/m173 pattern); vectorized LayerNorm loads.
// Workspace requirement: ~230 MB.
// ---------------------------------------------------------------------------

typedef __attribute__((ext_vector_type(4))) float f32x4;
typedef __attribute__((ext_vector_type(8))) __bf16 bf16x8;
typedef __attribute__((ext_vector_type(4))) __bf16 bf16x4;

#define BATCH 32
#define SEQL  512
#define DIM   1024
#define HEADS 16
#define DH    64
#define LTOT  68          // 4 mean-pool latents + 64 learned
#define KEYS  580         // SEQL + LTOT
#define HID   4096
#define LN_EPS 1e-5f

__device__ __forceinline__ float bf2f(__bf16 v) { return (float)v; }
__device__ __forceinline__ __bf16 f2bf(float v) { return (__bf16)v; }

// async 16B global -> LDS (wave-uniform LDS base + lane*16)
__device__ __forceinline__ void gld_lds16(const __bf16* g, __bf16* l) {
    __builtin_amdgcn_global_load_lds(
        (const __attribute__((address_space(1))) void*)g,
        (__attribute__((address_space(3))) void*)l, 16, 0, 0);
}

// ---------------- block-wide 2-value sum reduction (256 threads) ------------
__device__ __forceinline__ void block_reduce2(float& a, float& b, float* red) {
#pragma unroll
    for (int m = 32; m > 0; m >>= 1) {
        a += __shfl_xor(a, m, 64);
        b += __shfl_xor(b, m, 64);
    }
    int wid = threadIdx.x >> 6, lane = threadIdx.x & 63;
    __syncthreads();                    // protect red[] reuse across calls
    if (lane == 0) { red[wid] = a; red[4 + wid] = b; }
    __syncthreads();
    a = red[0] + red[1] + red[2] + red[3];
    b = red[4] + red[5] + red[6] + red[7];
}

// ---------------- x_pos = bf16(x + pos_emb) --------------------------------
__global__ __launch_bounds__(256) void add_pos(const float* __restrict__ x,
                                               const float* __restrict__ pos,
                                               __bf16* __restrict__ xp) {
    const int total4 = (BATCH * SEQL * DIM) / 4;   // 4,194,304
    const int pos4m = (SEQL * DIM) / 4 - 1;        // 131071 (pow2-1)
    for (int i = blockIdx.x * 256 + threadIdx.x; i < total4; i += gridDim.x * 256) {
        f32x4 xv = ((const f32x4*)x)[i];
        f32x4 pv = ((const f32x4*)pos)[i & pos4m];
        bf16x4 o;
#pragma unroll
        for (int j = 0; j < 4; ++j) o[j] = f2bf(xv[j] + pv[j]);
        ((bf16x4*)xp)[i] = o;
    }
}

// ---------------- pooled[b][d] = mean_s x[b,s,d] ---------------------------
__global__ __launch_bounds__(256) void pool_mean(const float* __restrict__ x,
                                                 float* __restrict__ pooled) {
    int b = blockIdx.x >> 2;
    int d = ((blockIdx.x & 3) << 8) + threadIdx.x;
    const float* p = x + (size_t)b * SEQL * DIM + d;
    float s = 0.f;
    for (int ss = 0; ss < SEQL; ++ss) s += p[(size_t)ss * DIM];
    pooled[b * DIM + d] = s * (1.f / SEQL);
}

// ---------------- lat rows 4..67 = latents ---------------------------------
__global__ __launch_bounds__(256) void lat_fill(const float* __restrict__ latents,
                                                float* __restrict__ lat) {
    int i = blockIdx.x * 256 + threadIdx.x;        // < 524288
    int b = i >> 14;
    int rem = i & 16383;
    int r = rem >> 8, d4 = rem & 255;
    ((f32x4*)lat)[(size_t)(b * LTOT + 4 + r) * 256 + d4] = ((const f32x4*)latents)[rem];
}

// ---------------- row LayerNorm -> bf16 (vectorized) ------------------------
// STD: (x-mean)*rstd*w + b   ;  !STD (custom): (x-mean)*rstd*w
template <typename Tin, bool STD, int COLS>
__global__ __launch_bounds__(256) void ln_rows(const Tin* __restrict__ in,
                                               __bf16* __restrict__ out,
                                               const float* __restrict__ w,
                                               const float* __restrict__ bb) {
    __shared__ float red[8];
    constexpr int NPT = COLS / 256;     // 4 (DIM) or 16 (HID)
    size_t base = (size_t)blockIdx.x * COLS;
    int t = threadIdx.x;
    int c0 = t * NPT;
    float xv[NPT];
    float s = 0.f, s2 = 0.f;
#pragma unroll
    for (int k4 = 0; k4 < NPT / 4; ++k4) {
        if constexpr (sizeof(Tin) == 2) {
            bf16x4 v = *(const bf16x4*)(in + base + c0 + k4 * 4);
#pragma unroll
            for (int e = 0; e < 4; ++e) {
                float f = bf2f(v[e]);
                xv[k4 * 4 + e] = f; s += f; s2 += f * f;
            }
        } else {
            f32x4 v = *(const f32x4*)((const float*)in + base + c0 + k4 * 4);
#pragma unroll
            for (int e = 0; e < 4; ++e) {
                float f = v[e];
                xv[k4 * 4 + e] = f; s += f; s2 += f * f;
            }
        }
    }
    block_reduce2(s, s2, red);
    float mean = s * (1.f / COLS);
    float var = s2 * (1.f / COLS) - mean * mean;
    float rstd = rsqrtf(var + LN_EPS);
#pragma unroll
    for (int k4 = 0; k4 < NPT / 4; ++k4) {
        f32x4 wv = *(const f32x4*)(w + c0 + k4 * 4);
        f32x4 bv;
        if (STD) bv = *(const f32x4*)(bb + c0 + k4 * 4);
        bf16x4 o;
#pragma unroll
        for (int e = 0; e < 4; ++e) {
            float y = (xv[k4 * 4 + e] - mean) * rstd * wv[e];
            if (STD) y += bv[e];
            o[e] = f2bf(y);
        }
        *(bf16x4*)(out + base + c0 + k4 * 4) = o;
    }
}

// ------- fused: lat = std_ln(gin)*w+b + lat ; ffin = custom_ln(lat)*g1 -----
__global__ __launch_bounds__(256) void wout_ln_res(const float* __restrict__ gin,
                                                   float* __restrict__ lat,
                                                   __bf16* __restrict__ ffin,
                                                   const float* __restrict__ w,
                                                   const float* __restrict__ b,
                                                   const float* __restrict__ g1) {
    __shared__ float red[8];
    size_t base = (size_t)blockIdx.x * DIM;
    int t = threadIdx.x;
    float xv[4];
    float s = 0.f, s2 = 0.f;
#pragma unroll
    for (int k = 0; k < 4; ++k) {
        float v = gin[base + t + (k << 8)];
        xv[k] = v; s += v; s2 += v * v;
    }
    block_reduce2(s, s2, red);
    float mean = s * (1.f / DIM);
    float var = s2 * (1.f / DIM) - mean * mean;
    float rstd = rsqrtf(var + LN_EPS);
    float yv[4];
    s = 0.f; s2 = 0.f;
#pragma unroll
    for (int k = 0; k < 4; ++k) {
        int c = t + (k << 8);
        float y = (xv[k] - mean) * rstd * w[c] + b[c] + lat[base + c];
        yv[k] = y; s += y; s2 += y * y;
        lat[base + c] = y;
    }
    block_reduce2(s, s2, red);
    float mean2 = s * (1.f / DIM);
    float var2 = s2 * (1.f / DIM) - mean2 * mean2;
    float rstd2 = rsqrtf(var2 + LN_EPS);
#pragma unroll
    for (int k = 0; k < 4; ++k) {
        int c = t + (k << 8);
        ffin[base + c] = f2bf((yv[k] - mean2) * rstd2 * g1[c]);
    }
}

// ---------------- transpose + cast: in[K,N] f32 -> out[N,K] bf16 -----------
__global__ __launch_bounds__(256) void transpose_cast(const float* __restrict__ in,
                                                      __bf16* __restrict__ out,
                                                      int K, int N) {
    __shared__ float tile[32][33];
    int n0 = blockIdx.x * 32, k0 = blockIdx.y * 32;
    int tx = threadIdx.x & 31, ty = threadIdx.x >> 5;
#pragma unroll
    for (int p = 0; p < 4; ++p) {
        int kk = ty + p * 8;
        tile[kk][tx] = in[(size_t)(k0 + kk) * N + n0 + tx];
    }
    __syncthreads();
#pragma unroll
    for (int p = 0; p < 4; ++p) {
        int nn = ty + p * 8;
        out[(size_t)(n0 + nn) * K + k0 + tx] = f2bf(tile[tx][nn]);
    }
}

// ---------------- bf16 MFMA GEMM: C = A[M,K] @ Bt[N,K]^T -------------------
// 128x128 tile, BK=64, 4 waves (2x2), 16x16x32 MFMA.
// Staging: global_load_lds dwordx4, linear LDS dest, pre-swizzled source so
// LDS[r][chunk c] = global chunk (c ^ (r&7)); read side XORs back.
// EPI: 0=f32, 1=bf16, 2=bf16*scale, 3=gelu->f32, 4=f32 + Cres
template <int EPI>
__global__ __launch_bounds__(256) void gemm_bf16(
    const __bf16* __restrict__ A, const __bf16* __restrict__ Bt,
    void* __restrict__ Cout, const float* __restrict__ bias,
    const float* __restrict__ Cres,
    int M, int N, int K, int batch_rows, long long batch_stride, int ldc,
    float scale) {
    __shared__ __bf16 As[128][64];
    __shared__ __bf16 Bs[128][64];
    const int t = threadIdx.x;
    const int m0 = blockIdx.y * 128, n0 = blockIdx.x * 128;
    const int wid = t >> 6, lane = t & 63;
    const int wr = wid >> 1, wc = wid & 1;
    const int lrow = lane & 15;
    const int lr = lane >> 3, lc = lane & 7;       // staging row-in-8 / chunk
    const int src_col = (lc ^ lr) << 3;            // pre-swizzled source col
    f32x4 acc[4][4] = {};

    // clamped global rows for the 4 staging iterations (wave w covers rows
    // w*8 + it*32 .. +7; rowbase multiple of 8 so r&7 == lr)
    int garow[4], gbrow[4];
#pragma unroll
    for (int it = 0; it < 4; ++it) {
        int r = wid * 8 + it * 32 + lr;
        int gm = m0 + r; garow[it] = gm < M ? gm : M - 1;
        int gn = n0 + r; gbrow[it] = gn < N ? gn : N - 1;
    }

    for (int kt = 0; kt < K; kt += 64) {
#pragma unroll
        for (int it = 0; it < 4; ++it) {
            int rb = wid * 8 + it * 32;
            gld_lds16(A + (size_t)garow[it] * K + kt + src_col, &As[rb][0]);
            gld_lds16(Bt + (size_t)gbrow[it] * K + kt + src_col, &Bs[rb][0]);
        }
        __syncthreads();
#pragma unroll
        for (int kc = 0; kc < 2; ++kc) {
            const int ck = (kc << 2) + (lane >> 4);
            bf16x8 af[4], bfr[4];
#pragma unroll
            for (int f = 0; f < 4; ++f) {
                int ra = wr * 64 + f * 16 + lrow;
                af[f] = *(const bf16x8*)(&As[ra][(ck ^ (ra & 7)) << 3]);
                int rb = wc * 64 + f * 16 + lrow;
                bfr[f] = *(const bf16x8*)(&Bs[rb][(ck ^ (rb & 7)) << 3]);
            }
#pragma unroll
            for (int fm = 0; fm < 4; ++fm)
#pragma unroll
                for (int fn = 0; fn < 4; ++fn)
                    acc[fm][fn] = __builtin_amdgcn_mfma_f32_16x16x32_bf16(
                        af[fm], bfr[fn], acc[fm][fn], 0, 0, 0);
        }
        __syncthreads();
    }
    // epilogue: C/D layout col=lane&15, row=(lane>>4)*4+j  [m89]
    const int rbase = (lane >> 4) << 2;
    const int cofs = lane & 15;
#pragma unroll
    for (int fm = 0; fm < 4; ++fm) {
#pragma unroll
        for (int j = 0; j < 4; ++j) {
            int m = m0 + wr * 64 + fm * 16 + rbase + j;
            if (m >= M) continue;
            long long roff = (long long)(m / batch_rows) * batch_stride +
                             (long long)(m % batch_rows) * ldc;
#pragma unroll
            for (int fn = 0; fn < 4; ++fn) {
                int n = n0 + wc * 64 + fn * 16 + cofs;
                if (n >= N) continue;
                float v = acc[fm][fn][j];
                if (bias) v += bias[n];
                if (EPI == 0) ((float*)Cout)[roff + n] = v;
                else if (EPI == 1) ((__bf16*)Cout)[roff + n] = f2bf(v);
                else if (EPI == 2) ((__bf16*)Cout)[roff + n] = f2bf(v * scale);
                else if (EPI == 3) ((float*)Cout)[roff + n] =
                    0.5f * v * (1.0f + erff(v * 0.70710678118654752f));
                else ((float*)Cout)[roff + n] = v + Cres[roff + n];
            }
        }
    }
}

// ---------------- fused flash attention per (b,h) --------------------------
// q: [B, 68, 1024] bf16 (pre-scaled); kv: [B, 580, 2048] bf16; out bf16.
__global__ __launch_bounds__(256) void attn_kernel(const __bf16* __restrict__ q,
                                                   const __bf16* __restrict__ kv,
                                                   __bf16* __restrict__ out) {
    __shared__ float qs_f[LTOT][64];    // 17408 B
    __shared__ __bf16 ks[64][64];       // 8192 B (chunk-swizzled)
    __shared__ float vs_f[64][64];      // 16384 B
    __shared__ float ps[LTOT][65];      // 17680 B (padded)
    __shared__ float scale_s[LTOT], l_s[LTOT];

    const int t = threadIdx.x;
    const int b = blockIdx.x >> 4;
    const int h = blockIdx.x & 15;

    const __bf16* qbase = q + (size_t)b * LTOT * DIM + h * DH;
    for (int cc = t; cc < LTOT * 8; cc += 256) {
        int r = cc >> 3, c8 = cc & 7;
        bf16x8 v = *(const bf16x8*)(qbase + (size_t)r * DIM + (c8 << 3));
#pragma unroll
        for (int e = 0; e < 8; ++e) qs_f[r][(c8 << 3) + e] = bf2f(v[e]);
    }

    float av[2][16];
#pragma unroll
    for (int s2 = 0; s2 < 2; ++s2)
#pragma unroll
        for (int e = 0; e < 16; ++e) av[s2][e] = 0.f;
    float m_r = -1e30f, l_r = 0.f;

    const __bf16* kbase = kv + (size_t)b * KEYS * 2048 + h * DH;
    const __bf16* vbase = kbase + 1024;

    for (int jt = 0; jt < 10; ++jt) {
        const int j0 = jt << 6;
        __syncthreads();
#pragma unroll
        for (int p = 0; p < 2; ++p) {
            int cc = t + (p << 8);
            int jj = cc >> 3, c8 = cc & 7;
            int j = j0 + jj;
            bf16x8 kk = {}, vv = {};
            if (j < KEYS) {
                kk = *(const bf16x8*)(kbase + (size_t)j * 2048 + (c8 << 3));
                vv = *(const bf16x8*)(vbase + (size_t)j * 2048 + (c8 << 3));
            }
            *(bf16x8*)(&ks[jj][(c8 ^ (jj & 7)) << 3]) = kk;
#pragma unroll
            for (int e = 0; e < 8; ++e) vs_f[jj][(c8 << 3) + e] = bf2f(vv[e]);
        }
        __syncthreads();
        for (int idx = t; idx < LTOT * 64; idx += 256) {
            int r = idx >> 6, jj = idx & 63;
            float s = 0.f;
#pragma unroll
            for (int c8 = 0; c8 < 8; ++c8) {
                const f32x4* qp = (const f32x4*)(&qs_f[r][c8 << 3]);
                f32x4 q0 = qp[0], q1 = qp[1];
                bf16x8 kk = *(const bf16x8*)(&ks[jj][(c8 ^ (jj & 7)) << 3]);
#pragma unroll
                for (int e = 0; e < 4; ++e) {
                    s += q0[e] * bf2f(kk[e]);
                    s += q1[e] * bf2f(kk[4 + e]);
                }
            }
            ps[r][jj] = (j0 + jj < KEYS) ? s : -3.0e38f;
        }
        __syncthreads();
        if (t < LTOT) {
            float tm = -3.0e38f;
            for (int jj = 0; jj < 64; ++jj) tm = fmaxf(tm, ps[t][jj]);
            float mnew = fmaxf(m_r, tm);
            float sc = __expf(m_r - mnew);
            float sum = 0.f;
            for (int jj = 0; jj < 64; ++jj) {
                float pv = __expf(ps[t][jj] - mnew);
                ps[t][jj] = pv;
                sum += pv;
            }
            l_r = l_r * sc + sum;
            m_r = mnew;
            scale_s[t] = sc;
        }
        __syncthreads();
#pragma unroll
        for (int s2 = 0; s2 < 2; ++s2) {
            int slot = t + (s2 << 8);
            if (slot < LTOT * 4) {
                int r = slot >> 2, d0 = (slot & 3) << 4;
                float sc = scale_s[r];
#pragma unroll
                for (int e = 0; e < 16; ++e) av[s2][e] *= sc;
                for (int jj = 0; jj < 64; ++jj) {
                    float p = ps[r][jj];
                    const f32x4* vp = (const f32x4*)(&vs_f[jj][d0]);
                    f32x4 v0 = vp[0], v1 = vp[1], v2 = vp[2], v3 = vp[3];
#pragma unroll
                    for (int e = 0; e < 4; ++e) {
                        av[s2][e] += p * v0[e];
                        av[s2][4 + e] += p * v1[e];
                        av[s2][8 + e] += p * v2[e];
                        av[s2][12 + e] += p * v3[e];
                    }
                }
            }
        }
    }
    if (t < LTOT) l_s[t] = l_r;
    __syncthreads();
    __bf16* obase = out + (size_t)b * LTOT * DIM + h * DH;
#pragma unroll
    for (int s2 = 0; s2 < 2; ++s2) {
        int slot = t + (s2 << 8);
        if (slot < LTOT * 4) {
            int r = slot >> 2, d0 = (slot & 3) << 4;
            float inv = 1.f / l_s[r];
#pragma unroll
            for (int e = 0; e < 16; ++e)
                obase[(size_t)r * DIM + d0 + e] = f2bf(av[s2][e] * inv);
        }
    }
}

// ---------------------------------------------------------------------------
static void launch_gemm(int epi, const __bf16* A, const __bf16* Bt, void* C,
                        const float* bias, const float* Cres, int M, int N, int K,
                        int br, long long bs, int ldc, float scale,
                        hipStream_t stream) {
    dim3 g(N / 128, (M + 127) / 128), blk(256);
    switch (epi) {
        case 0: gemm_bf16<0><<<g, blk, 0, stream>>>(A, Bt, C, bias, Cres, M, N, K, br, bs, ldc, scale); break;
        case 1: gemm_bf16<1><<<g, blk, 0, stream>>>(A, Bt, C, bias, Cres, M, N, K, br, bs, ldc, scale); break;
        case 2: gemm_bf16<2><<<g, blk, 0, stream>>>(A, Bt, C, bias, Cres, M, N, K, br, bs, ldc, scale); break;
        case 3: gemm_bf16<3><<<g, blk, 0, stream>>>(A, Bt, C, bias, Cres, M, N, K, br, bs, ldc, scale); break;
        default: gemm_bf16<4><<<g, blk, 0, stream>>>(A, Bt, C, bias, Cres, M, N, K, br, bs, ldc, scale); break;
    }
}

extern "C" void kernel_launch(void* const* d_in, const int* in_sizes, int n_in,
                              void* d_out, int out_size, void* d_ws, size_t ws_size,
                              hipStream_t stream) {
    (void)in_sizes; (void)n_in; (void)out_size; (void)ws_size;
    const float* x          = (const float*)d_in[0];
    // d_in[1] mask: all-true, unused
    const float* pos_emb    = (const float*)d_in[2];
    const float* latents    = (const float*)d_in[3];
    const float* mp_ln_g    = (const float*)d_in[4];
    const float* mp_w       = (const float*)d_in[5];
    const float* mp_b       = (const float*)d_in[6];
    const float* attn_norm_w= (const float*)d_in[7];
    const float* attn_norm_b= (const float*)d_in[8];
    const float* attn_lat_w = (const float*)d_in[9];
    const float* attn_lat_b = (const float*)d_in[10];
    const float* Wq         = (const float*)d_in[11];
    const float* Wkv        = (const float*)d_in[12];
    const float* Wout       = (const float*)d_in[13];
    const float* out_ln_w   = (const float*)d_in[14];
    const float* out_ln_b   = (const float*)d_in[15];
    const float* ff_ln1_g   = (const float*)d_in[16];
    const float* ff_w1      = (const float*)d_in[17];
    const float* ff_ln2_g   = (const float*)d_in[18];
    const float* ff_w2      = (const float*)d_in[19];

    float* lat = (float*)d_out;                    // residual stream, f32

    char* ws = (char*)d_ws;
    size_t off = 0;
    auto take = [&](size_t bytes) -> char* {
        char* p = ws + off;
        off += (bytes + 255) & ~(size_t)255;
        return p;
    };
    __bf16* xpos = (__bf16*)take(2ULL * BATCH * SEQL * DIM);
    __bf16* xn   = (__bf16*)take(2ULL * BATCH * SEQL * DIM);
    __bf16* lnl  = (__bf16*)take(2ULL * BATCH * LTOT * DIM);
    __bf16* ffin = (__bf16*)take(2ULL * BATCH * LTOT * DIM);
    __bf16* qb   = (__bf16*)take(2ULL * BATCH * LTOT * DIM);
    __bf16* ao   = (__bf16*)take(2ULL * BATCH * LTOT * DIM);
    __bf16* kvb  = (__bf16*)take(2ULL * BATCH * KEYS * 2048);
    float*  gout = (float*)take(4ULL * BATCH * LTOT * HID);
    __bf16* h2   = (__bf16*)take(2ULL * BATCH * LTOT * HID);
    __bf16* wT   = (__bf16*)take(2ULL * 12 * 1024 * 1024);
    float*  pooled = (float*)take(4ULL * BATCH * DIM);
    __bf16* mpin = (__bf16*)take(2ULL * BATCH * DIM);

    __bf16* wqT   = wT;                    // [1024,1024]
    __bf16* wkvT  = wT + 1 * 1024 * 1024;  // [2048,1024]
    __bf16* woutT = wT + 3 * 1024 * 1024;  // [1024,1024]
    __bf16* f1T   = wT + 4 * 1024 * 1024;  // [4096,1024]
    __bf16* f2T   = wT + 8 * 1024 * 1024;  // [1024,4096]
    __bf16* mpwT  = wT;                    // [4096,1024], used before layers

    // ---- prologue -----------------------------------------------------
    add_pos<<<4096, 256, 0, stream>>>(x, pos_emb, xpos);
    pool_mean<<<128, 256, 0, stream>>>(x, pooled);
    ln_rows<float, false, DIM><<<BATCH, 256, 0, stream>>>(pooled, mpin, mp_ln_g, nullptr);
    transpose_cast<<<dim3(4096 / 32, 1024 / 32), 256, 0, stream>>>(mp_w, mpwT, 1024, 4096);
    // mp_lat -> lat rows 0..3 per batch (ldc = 68*1024 puts n in [0,4096) there)
    launch_gemm(0, mpin, mpwT, lat, mp_b, nullptr, BATCH, 4096, 1024,
                BATCH, 0, LTOT * DIM, 1.f, stream);
    lat_fill<<<2048, 256, 0, stream>>>(latents, lat);

    // ---- layers -------------------------------------------------------
    for (int i = 0; i < 4; ++i) {
        transpose_cast<<<dim3(32, 32), 256, 0, stream>>>(Wq + (size_t)i * 1024 * 1024, wqT, 1024, 1024);
        transpose_cast<<<dim3(64, 32), 256, 0, stream>>>(Wkv + (size_t)i * 1024 * 2048, wkvT, 1024, 2048);
        transpose_cast<<<dim3(32, 32), 256, 0, stream>>>(Wout + (size_t)i * 1024 * 1024, woutT, 1024, 1024);
        transpose_cast<<<dim3(128, 32), 256, 0, stream>>>(ff_w1 + (size_t)i * 1024 * 4096, f1T, 1024, 4096);
        transpose_cast<<<dim3(32, 128), 256, 0, stream>>>(ff_w2 + (size_t)i * 4096 * 1024, f2T, 4096, 1024);

        ln_rows<__bf16, true, DIM><<<BATCH * SEQL, 256, 0, stream>>>(
            xpos, xn, attn_norm_w + i * DIM, attn_norm_b + i * DIM);
        ln_rows<float, true, DIM><<<BATCH * LTOT, 256, 0, stream>>>(
            lat, lnl, attn_lat_w + i * DIM, attn_lat_b + i * DIM);

        // q = (lnl @ Wq) * 0.125  -> bf16
        launch_gemm(2, lnl, wqT, qb, nullptr, nullptr, BATCH * LTOT, 1024, 1024,
                    BATCH * LTOT, 0, 1024, 0.125f, stream);
        // kv rows 0..511 per batch from xn
        launch_gemm(1, xn, wkvT, kvb, nullptr, nullptr, BATCH * SEQL, 2048, 1024,
                    SEQL, (long long)KEYS * 2048, 2048, 1.f, stream);
        // kv rows 512..579 per batch from lnl
        launch_gemm(1, lnl, wkvT, kvb + 512 * 2048, nullptr, nullptr, BATCH * LTOT, 2048, 1024,
                    LTOT, (long long)KEYS * 2048, 2048, 1.f, stream);

        attn_kernel<<<BATCH * HEADS, 256, 0, stream>>>(qb, kvb, ao);

        launch_gemm(0, ao, woutT, gout, nullptr, nullptr, BATCH * LTOT, 1024, 1024,
                    BATCH * LTOT, 0, 1024, 1.f, stream);
        wout_ln_res<<<BATCH * LTOT, 256, 0, stream>>>(
            gout, lat, ffin, out_ln_w + i * DIM, out_ln_b + i * DIM, ff_ln1_g + i * DIM);

        launch_gemm(3, ffin, f1T, gout, nullptr, nullptr, BATCH * LTOT, HID, 1024,
                    BATCH * LTOT, 0, HID, 1.f, stream);
        ln_rows<float, false, HID><<<BATCH * LTOT, 256, 0, stream>>>(
            gout, h2, ff_ln2_g + i * HID, nullptr);
        launch_gemm(4, h2, f2T, lat, nullptr, lat, BATCH * LTOT, 1024, HID,
                    BATCH * LTOT, 0, 1024, 1.f, stream);
    }
}

// Round 3
// 2439.811 us; speedup vs baseline: 1.5163x; 1.0857x over previous
//
#include <hip/hip_runtime.h>

// ---------------------------------------------------------------------------
// PerceiverResampler forward, MI355X gfx950.
// Residual stream (lat) lives in d_out (f32). bf16 MFMA GEMMs, f32 accum.
// R3: MFMA attention (qk_gemm -> row softmax -> pv_gemm with V^T transpose),
// replacing the VALU/LDS-bound attn_kernel (181us -> ~20us/layer predicted).
// Workspace requirement: ~261 MB.
// ---------------------------------------------------------------------------

typedef __attribute__((ext_vector_type(4))) float f32x4;
typedef __attribute__((ext_vector_type(8))) __bf16 bf16x8;
typedef __attribute__((ext_vector_type(4))) __bf16 bf16x4;

#define BATCH 32
#define SEQL  512
#define DIM   1024
#define HEADS 16
#define DH    64
#define LTOT  68          // 4 mean-pool latents + 64 learned
#define KEYS  580         // SEQL + LTOT
#define KPAD  640         // KEYS padded to 5*128
#define HID   4096
#define LN_EPS 1e-5f

__device__ __forceinline__ float bf2f(__bf16 v) { return (float)v; }
__device__ __forceinline__ __bf16 f2bf(float v) { return (__bf16)v; }

// async 16B global -> LDS (wave-uniform LDS base + lane*16)
__device__ __forceinline__ void gld_lds16(const __bf16* g, __bf16* l) {
    __builtin_amdgcn_global_load_lds(
        (const __attribute__((address_space(1))) void*)g,
        (__attribute__((address_space(3))) void*)l, 16, 0, 0);
}

// ---------------- block-wide 2-value sum reduction (256 threads) ------------
__device__ __forceinline__ void block_reduce2(float& a, float& b, float* red) {
#pragma unroll
    for (int m = 32; m > 0; m >>= 1) {
        a += __shfl_xor(a, m, 64);
        b += __shfl_xor(b, m, 64);
    }
    int wid = threadIdx.x >> 6, lane = threadIdx.x & 63;
    __syncthreads();                    // protect red[] reuse across calls
    if (lane == 0) { red[wid] = a; red[4 + wid] = b; }
    __syncthreads();
    a = red[0] + red[1] + red[2] + red[3];
    b = red[4] + red[5] + red[6] + red[7];
}

// ---------------- x_pos = bf16(x + pos_emb) --------------------------------
__global__ __launch_bounds__(256) void add_pos(const float* __restrict__ x,
                                               const float* __restrict__ pos,
                                               __bf16* __restrict__ xp) {
    const int total4 = (BATCH * SEQL * DIM) / 4;   // 4,194,304
    const int pos4m = (SEQL * DIM) / 4 - 1;        // 131071 (pow2-1)
    for (int i = blockIdx.x * 256 + threadIdx.x; i < total4; i += gridDim.x * 256) {
        f32x4 xv = ((const f32x4*)x)[i];
        f32x4 pv = ((const f32x4*)pos)[i & pos4m];
        bf16x4 o;
#pragma unroll
        for (int j = 0; j < 4; ++j) o[j] = f2bf(xv[j] + pv[j]);
        ((bf16x4*)xp)[i] = o;
    }
}

// ---------------- pooled[b][d] = mean_s x[b,s,d] ---------------------------
__global__ __launch_bounds__(256) void pool_mean(const float* __restrict__ x,
                                                 float* __restrict__ pooled) {
    int b = blockIdx.x >> 2;
    int d = ((blockIdx.x & 3) << 8) + threadIdx.x;
    const float* p = x + (size_t)b * SEQL * DIM + d;
    float s = 0.f;
    for (int ss = 0; ss < SEQL; ++ss) s += p[(size_t)ss * DIM];
    pooled[b * DIM + d] = s * (1.f / SEQL);
}

// ---------------- lat rows 4..67 = latents ---------------------------------
__global__ __launch_bounds__(256) void lat_fill(const float* __restrict__ latents,
                                                float* __restrict__ lat) {
    int i = blockIdx.x * 256 + threadIdx.x;        // < 524288
    int b = i >> 14;
    int rem = i & 16383;
    int r = rem >> 8, d4 = rem & 255;
    ((f32x4*)lat)[(size_t)(b * LTOT + 4 + r) * 256 + d4] = ((const f32x4*)latents)[rem];
}

// ---------------- row LayerNorm -> bf16 (vectorized) ------------------------
template <typename Tin, bool STD, int COLS>
__global__ __launch_bounds__(256) void ln_rows(const Tin* __restrict__ in,
                                               __bf16* __restrict__ out,
                                               const float* __restrict__ w,
                                               const float* __restrict__ bb) {
    __shared__ float red[8];
    constexpr int NPT = COLS / 256;     // 4 (DIM) or 16 (HID)
    size_t base = (size_t)blockIdx.x * COLS;
    int t = threadIdx.x;
    int c0 = t * NPT;
    float xv[NPT];
    float s = 0.f, s2 = 0.f;
#pragma unroll
    for (int k4 = 0; k4 < NPT / 4; ++k4) {
        if constexpr (sizeof(Tin) == 2) {
            bf16x4 v = *(const bf16x4*)(in + base + c0 + k4 * 4);
#pragma unroll
            for (int e = 0; e < 4; ++e) {
                float f = bf2f(v[e]);
                xv[k4 * 4 + e] = f; s += f; s2 += f * f;
            }
        } else {
            f32x4 v = *(const f32x4*)((const float*)in + base + c0 + k4 * 4);
#pragma unroll
            for (int e = 0; e < 4; ++e) {
                float f = v[e];
                xv[k4 * 4 + e] = f; s += f; s2 += f * f;
            }
        }
    }
    block_reduce2(s, s2, red);
    float mean = s * (1.f / COLS);
    float var = s2 * (1.f / COLS) - mean * mean;
    float rstd = rsqrtf(var + LN_EPS);
#pragma unroll
    for (int k4 = 0; k4 < NPT / 4; ++k4) {
        f32x4 wv = *(const f32x4*)(w + c0 + k4 * 4);
        f32x4 bv;
        if (STD) bv = *(const f32x4*)(bb + c0 + k4 * 4);
        bf16x4 o;
#pragma unroll
        for (int e = 0; e < 4; ++e) {
            float y = (xv[k4 * 4 + e] - mean) * rstd * wv[e];
            if (STD) y += bv[e];
            o[e] = f2bf(y);
        }
        *(bf16x4*)(out + base + c0 + k4 * 4) = o;
    }
}

// ------- fused: lat = std_ln(gin)*w+b + lat ; ffin = custom_ln(lat)*g1 -----
__global__ __launch_bounds__(256) void wout_ln_res(const float* __restrict__ gin,
                                                   float* __restrict__ lat,
                                                   __bf16* __restrict__ ffin,
                                                   const float* __restrict__ w,
                                                   const float* __restrict__ b,
                                                   const float* __restrict__ g1) {
    __shared__ float red[8];
    size_t base = (size_t)blockIdx.x * DIM;
    int t = threadIdx.x;
    float xv[4];
    float s = 0.f, s2 = 0.f;
#pragma unroll
    for (int k = 0; k < 4; ++k) {
        float v = gin[base + t + (k << 8)];
        xv[k] = v; s += v; s2 += v * v;
    }
    block_reduce2(s, s2, red);
    float mean = s * (1.f / DIM);
    float var = s2 * (1.f / DIM) - mean * mean;
    float rstd = rsqrtf(var + LN_EPS);
    float yv[4];
    s = 0.f; s2 = 0.f;
#pragma unroll
    for (int k = 0; k < 4; ++k) {
        int c = t + (k << 8);
        float y = (xv[k] - mean) * rstd * w[c] + b[c] + lat[base + c];
        yv[k] = y; s += y; s2 += y * y;
        lat[base + c] = y;
    }
    block_reduce2(s, s2, red);
    float mean2 = s * (1.f / DIM);
    float var2 = s2 * (1.f / DIM) - mean2 * mean2;
    float rstd2 = rsqrtf(var2 + LN_EPS);
#pragma unroll
    for (int k = 0; k < 4; ++k) {
        int c = t + (k << 8);
        ffin[base + c] = f2bf((yv[k] - mean2) * rstd2 * g1[c]);
    }
}

// ---------------- transpose + cast: in[K,N] f32 -> out[N,K] bf16 -----------
__global__ __launch_bounds__(256) void transpose_cast(const float* __restrict__ in,
                                                      __bf16* __restrict__ out,
                                                      int K, int N) {
    __shared__ float tile[32][33];
    int n0 = blockIdx.x * 32, k0 = blockIdx.y * 32;
    int tx = threadIdx.x & 31, ty = threadIdx.x >> 5;
#pragma unroll
    for (int p = 0; p < 4; ++p) {
        int kk = ty + p * 8;
        tile[kk][tx] = in[(size_t)(k0 + kk) * N + n0 + tx];
    }
    __syncthreads();
#pragma unroll
    for (int p = 0; p < 4; ++p) {
        int nn = ty + p * 8;
        out[(size_t)(n0 + nn) * K + k0 + tx] = f2bf(tile[tx][nn]);
    }
}

// ---------------- bf16 MFMA GEMM: C = A[M,K] @ Bt[N,K]^T -------------------
// 128x128 tile, BK=64, 4 waves (2x2), 16x16x32 MFMA.
// Staging: global_load_lds dwordx4, linear LDS dest, pre-swizzled source.
// EPI: 0=f32, 1=bf16, 2=bf16*scale, 3=gelu->f32, 4=f32 + Cres
template <int EPI>
__global__ __launch_bounds__(256) void gemm_bf16(
    const __bf16* __restrict__ A, const __bf16* __restrict__ Bt,
    void* __restrict__ Cout, const float* __restrict__ bias,
    const float* __restrict__ Cres,
    int M, int N, int K, int batch_rows, long long batch_stride, int ldc,
    float scale) {
    __shared__ __bf16 As[128][64];
    __shared__ __bf16 Bs[128][64];
    const int t = threadIdx.x;
    const int m0 = blockIdx.y * 128, n0 = blockIdx.x * 128;
    const int wid = t >> 6, lane = t & 63;
    const int wr = wid >> 1, wc = wid & 1;
    const int lrow = lane & 15;
    const int lr = lane >> 3, lc = lane & 7;       // staging row-in-8 / chunk
    const int src_col = (lc ^ lr) << 3;            // pre-swizzled source col
    f32x4 acc[4][4] = {};

    int garow[4], gbrow[4];
#pragma unroll
    for (int it = 0; it < 4; ++it) {
        int r = wid * 8 + it * 32 + lr;
        int gm = m0 + r; garow[it] = gm < M ? gm : M - 1;
        int gn = n0 + r; gbrow[it] = gn < N ? gn : N - 1;
    }

    for (int kt = 0; kt < K; kt += 64) {
#pragma unroll
        for (int it = 0; it < 4; ++it) {
            int rb = wid * 8 + it * 32;
            gld_lds16(A + (size_t)garow[it] * K + kt + src_col, &As[rb][0]);
            gld_lds16(Bt + (size_t)gbrow[it] * K + kt + src_col, &Bs[rb][0]);
        }
        __syncthreads();
#pragma unroll
        for (int kc = 0; kc < 2; ++kc) {
            const int ck = (kc << 2) + (lane >> 4);
            bf16x8 af[4], bfr[4];
#pragma unroll
            for (int f = 0; f < 4; ++f) {
                int ra = wr * 64 + f * 16 + lrow;
                af[f] = *(const bf16x8*)(&As[ra][(ck ^ (ra & 7)) << 3]);
                int rb = wc * 64 + f * 16 + lrow;
                bfr[f] = *(const bf16x8*)(&Bs[rb][(ck ^ (rb & 7)) << 3]);
            }
#pragma unroll
            for (int fm = 0; fm < 4; ++fm)
#pragma unroll
                for (int fn = 0; fn < 4; ++fn)
                    acc[fm][fn] = __builtin_amdgcn_mfma_f32_16x16x32_bf16(
                        af[fm], bfr[fn], acc[fm][fn], 0, 0, 0);
        }
        __syncthreads();
    }
    const int rbase = (lane >> 4) << 2;
    const int cofs = lane & 15;
#pragma unroll
    for (int fm = 0; fm < 4; ++fm) {
#pragma unroll
        for (int j = 0; j < 4; ++j) {
            int m = m0 + wr * 64 + fm * 16 + rbase + j;
            if (m >= M) continue;
            long long roff = (long long)(m / batch_rows) * batch_stride +
                             (long long)(m % batch_rows) * ldc;
#pragma unroll
            for (int fn = 0; fn < 4; ++fn) {
                int n = n0 + wc * 64 + fn * 16 + cofs;
                if (n >= N) continue;
                float v = acc[fm][fn][j];
                if (bias) v += bias[n];
                if (EPI == 0) ((float*)Cout)[roff + n] = v;
                else if (EPI == 1) ((__bf16*)Cout)[roff + n] = f2bf(v);
                else if (EPI == 2) ((__bf16*)Cout)[roff + n] = f2bf(v * scale);
                else if (EPI == 3) ((float*)Cout)[roff + n] =
                    0.5f * v * (1.0f + erff(v * 0.70710678118654752f));
                else ((float*)Cout)[roff + n] = v + Cres[roff + n];
            }
        }
    }
}

// ---------------- attention: S = Q @ K^T (MFMA) ----------------------------
// grid (512 bh, 5 ntiles). sp[bh][68][640] bf16.
__global__ __launch_bounds__(256) void qk_gemm(const __bf16* __restrict__ q,
                                               const __bf16* __restrict__ kv,
                                               __bf16* __restrict__ sp) {
    __shared__ __bf16 Qs[80][64];
    __shared__ __bf16 Ks[128][64];
    const int bh = blockIdx.x, b = bh >> 4, h = bh & 15;
    const int n0 = blockIdx.y * 128;
    const int t = threadIdx.x, wid = t >> 6, lane = t & 63;
    const __bf16* qbase = q + (size_t)b * LTOT * DIM + h * DH;
    const __bf16* kbase = kv + (size_t)b * KEYS * 2048 + h * DH;
    const bf16x8 zero8 = {};

    for (int s = t; s < 80 * 8; s += 256) {
        int r = s >> 3, c8 = s & 7;
        bf16x8 v = zero8;
        if (r < LTOT) v = *(const bf16x8*)(qbase + (size_t)r * DIM + (c8 << 3));
        *(bf16x8*)(&Qs[r][(c8 ^ (r & 7)) << 3]) = v;
    }
    for (int s = t; s < 128 * 8; s += 256) {
        int r = s >> 3, c8 = s & 7;
        int gk = n0 + r; if (gk >= KEYS) gk = KEYS - 1;   // finite pad
        bf16x8 v = *(const bf16x8*)(kbase + (size_t)gk * 2048 + (c8 << 3));
        *(bf16x8*)(&Ks[r][(c8 ^ (r & 7)) << 3]) = v;
    }
    __syncthreads();

    const int lrow = lane & 15;
    f32x4 acc[5][2] = {};
#pragma unroll
    for (int kc = 0; kc < 2; ++kc) {
        const int ck = (kc << 2) + (lane >> 4);
        bf16x8 bfr[2];
#pragma unroll
        for (int fn = 0; fn < 2; ++fn) {
            int rb = wid * 32 + fn * 16 + lrow;
            bfr[fn] = *(const bf16x8*)(&Ks[rb][(ck ^ (rb & 7)) << 3]);
        }
#pragma unroll
        for (int fm = 0; fm < 5; ++fm) {
            int ra = fm * 16 + lrow;
            bf16x8 af = *(const bf16x8*)(&Qs[ra][(ck ^ (ra & 7)) << 3]);
#pragma unroll
            for (int fn = 0; fn < 2; ++fn)
                acc[fm][fn] = __builtin_amdgcn_mfma_f32_16x16x32_bf16(
                    af, bfr[fn], acc[fm][fn], 0, 0, 0);
        }
    }
    __bf16* srow = sp + (size_t)bh * LTOT * KPAD;
    const int rbase = (lane >> 4) << 2, cofs = lane & 15;
#pragma unroll
    for (int fm = 0; fm < 5; ++fm)
#pragma unroll
        for (int j = 0; j < 4; ++j) {
            int r = fm * 16 + rbase + j;
            if (r >= LTOT) continue;
#pragma unroll
            for (int fn = 0; fn < 2; ++fn) {
                int col = n0 + wid * 32 + fn * 16 + cofs;
                srow[(size_t)r * KPAD + col] = f2bf(acc[fm][fn][j]);
            }
        }
}

// ---------------- row softmax in place, writes P/l, zeros for pad ----------
__global__ __launch_bounds__(256) void softmax_p(__bf16* __restrict__ sp) {
    const int row = blockIdx.x * 4 + (threadIdx.x >> 6);
    const int lane = threadIdx.x & 63;
    __bf16* p = sp + (size_t)row * KPAD;
    float v[10];
    float m = -3.0e38f;
#pragma unroll
    for (int i = 0; i < 10; ++i) {
        int c = (i << 6) + lane;
        float f = (c < KEYS) ? bf2f(p[c]) : -3.0e38f;
        v[i] = f; m = fmaxf(m, f);
    }
#pragma unroll
    for (int mk = 32; mk > 0; mk >>= 1) m = fmaxf(m, __shfl_xor(m, mk, 64));
    float l = 0.f;
#pragma unroll
    for (int i = 0; i < 10; ++i) {
        int c = (i << 6) + lane;
        float e = (c < KEYS) ? __expf(v[i] - m) : 0.f;
        v[i] = e; l += e;
    }
#pragma unroll
    for (int mk = 32; mk > 0; mk >>= 1) l += __shfl_xor(l, mk, 64);
    float inv = 1.f / l;
#pragma unroll
    for (int i = 0; i < 10; ++i) {
        int c = (i << 6) + lane;
        p[c] = f2bf(v[i] * inv);
    }
}

// ---------------- vt[bh][d][k] = v[b][k][h*64+d] (bf16 copy-transpose) -----
// grid (512 bh, 20 ktiles, 2 dtiles)
__global__ __launch_bounds__(256) void vt_tr(const __bf16* __restrict__ kv,
                                             __bf16* __restrict__ vt) {
    __shared__ __bf16 tile[32][34];
    const int bh = blockIdx.x, b = bh >> 4, h = bh & 15;
    const int k0 = blockIdx.y * 32, d0 = blockIdx.z * 32;
    const int tx = threadIdx.x & 31, ty = threadIdx.x >> 5;
    const __bf16* vbase = kv + (size_t)b * KEYS * 2048 + 1024 + h * DH;
#pragma unroll
    for (int p = 0; p < 4; ++p) {
        int kk = k0 + ty + p * 8;
        int kc = kk < KEYS ? kk : KEYS - 1;
        tile[ty + p * 8][tx] = vbase[(size_t)kc * 2048 + d0 + tx];
    }
    __syncthreads();
    __bf16* obase = vt + (size_t)bh * DH * KPAD;
#pragma unroll
    for (int p = 0; p < 4; ++p) {
        int nn = ty + p * 8;
        __bf16 val = (k0 + tx < KEYS) ? tile[tx][nn] : (__bf16)0.f;
        obase[(size_t)(d0 + nn) * KPAD + k0 + tx] = val;
    }
}

// ---------------- O = P @ V (MFMA), grid 512 bh ----------------------------
__global__ __launch_bounds__(256) void pv_gemm(const __bf16* __restrict__ sp,
                                               const __bf16* __restrict__ vt,
                                               __bf16* __restrict__ ao) {
    __shared__ __bf16 Ps[80][64];
    __shared__ __bf16 Vs[64][64];
    const int bh = blockIdx.x, b = bh >> 4, h = bh & 15;
    const int t = threadIdx.x, wid = t >> 6, lane = t & 63;
    const int lrow = lane & 15;
    const __bf16* pbase = sp + (size_t)bh * LTOT * KPAD;
    const __bf16* vbase = vt + (size_t)bh * DH * KPAD;
    const bf16x8 zero8 = {};
    f32x4 acc[5] = {};

    for (int kt = 0; kt < KPAD; kt += 64) {
        for (int s = t; s < 80 * 8; s += 256) {
            int r = s >> 3, c8 = s & 7;
            bf16x8 v = zero8;
            if (r < LTOT) v = *(const bf16x8*)(pbase + (size_t)r * KPAD + kt + (c8 << 3));
            *(bf16x8*)(&Ps[r][(c8 ^ (r & 7)) << 3]) = v;
        }
        for (int s = t; s < 64 * 8; s += 256) {
            int r = s >> 3, c8 = s & 7;
            bf16x8 v = *(const bf16x8*)(vbase + (size_t)r * KPAD + kt + (c8 << 3));
            *(bf16x8*)(&Vs[r][(c8 ^ (r & 7)) << 3]) = v;
        }
        __syncthreads();
#pragma unroll
        for (int kc = 0; kc < 2; ++kc) {
            const int ck = (kc << 2) + (lane >> 4);
            int rb = wid * 16 + lrow;
            bf16x8 bfr = *(const bf16x8*)(&Vs[rb][(ck ^ (rb & 7)) << 3]);
#pragma unroll
            for (int fm = 0; fm < 5; ++fm) {
                int ra = fm * 16 + lrow;
                bf16x8 af = *(const bf16x8*)(&Ps[ra][(ck ^ (ra & 7)) << 3]);
                acc[fm] = __builtin_amdgcn_mfma_f32_16x16x32_bf16(
                    af, bfr, acc[fm], 0, 0, 0);
            }
        }
        __syncthreads();
    }
    __bf16* obase = ao + (size_t)b * LTOT * DIM + h * DH;
    const int rbase = (lane >> 4) << 2, cofs = lane & 15;
#pragma unroll
    for (int fm = 0; fm < 5; ++fm)
#pragma unroll
        for (int j = 0; j < 4; ++j) {
            int r = fm * 16 + rbase + j;
            if (r >= LTOT) continue;
            obase[(size_t)r * DIM + wid * 16 + cofs] = f2bf(acc[fm][j]);
        }
}

// ---------------------------------------------------------------------------
static void launch_gemm(int epi, const __bf16* A, const __bf16* Bt, void* C,
                        const float* bias, const float* Cres, int M, int N, int K,
                        int br, long long bs, int ldc, float scale,
                        hipStream_t stream) {
    dim3 g(N / 128, (M + 127) / 128), blk(256);
    switch (epi) {
        case 0: gemm_bf16<0><<<g, blk, 0, stream>>>(A, Bt, C, bias, Cres, M, N, K, br, bs, ldc, scale); break;
        case 1: gemm_bf16<1><<<g, blk, 0, stream>>>(A, Bt, C, bias, Cres, M, N, K, br, bs, ldc, scale); break;
        case 2: gemm_bf16<2><<<g, blk, 0, stream>>>(A, Bt, C, bias, Cres, M, N, K, br, bs, ldc, scale); break;
        case 3: gemm_bf16<3><<<g, blk, 0, stream>>>(A, Bt, C, bias, Cres, M, N, K, br, bs, ldc, scale); break;
        default: gemm_bf16<4><<<g, blk, 0, stream>>>(A, Bt, C, bias, Cres, M, N, K, br, bs, ldc, scale); break;
    }
}

extern "C" void kernel_launch(void* const* d_in, const int* in_sizes, int n_in,
                              void* d_out, int out_size, void* d_ws, size_t ws_size,
                              hipStream_t stream) {
    (void)in_sizes; (void)n_in; (void)out_size; (void)ws_size;
    const float* x          = (const float*)d_in[0];
    // d_in[1] mask: all-true, unused
    const float* pos_emb    = (const float*)d_in[2];
    const float* latents    = (const float*)d_in[3];
    const float* mp_ln_g    = (const float*)d_in[4];
    const float* mp_w       = (const float*)d_in[5];
    const float* mp_b       = (const float*)d_in[6];
    const float* attn_norm_w= (const float*)d_in[7];
    const float* attn_norm_b= (const float*)d_in[8];
    const float* attn_lat_w = (const float*)d_in[9];
    const float* attn_lat_b = (const float*)d_in[10];
    const float* Wq         = (const float*)d_in[11];
    const float* Wkv        = (const float*)d_in[12];
    const float* Wout       = (const float*)d_in[13];
    const float* out_ln_w   = (const float*)d_in[14];
    const float* out_ln_b   = (const float*)d_in[15];
    const float* ff_ln1_g   = (const float*)d_in[16];
    const float* ff_w1      = (const float*)d_in[17];
    const float* ff_ln2_g   = (const float*)d_in[18];
    const float* ff_w2      = (const float*)d_in[19];

    float* lat = (float*)d_out;                    // residual stream, f32

    char* ws = (char*)d_ws;
    size_t off = 0;
    auto take = [&](size_t bytes) -> char* {
        char* p = ws + off;
        off += (bytes + 255) & ~(size_t)255;
        return p;
    };
    __bf16* xpos = (__bf16*)take(2ULL * BATCH * SEQL * DIM);
    __bf16* xn   = (__bf16*)take(2ULL * BATCH * SEQL * DIM);
    __bf16* lnl  = (__bf16*)take(2ULL * BATCH * LTOT * DIM);
    __bf16* ffin = (__bf16*)take(2ULL * BATCH * LTOT * DIM);
    __bf16* qb   = (__bf16*)take(2ULL * BATCH * LTOT * DIM);
    __bf16* ao   = (__bf16*)take(2ULL * BATCH * LTOT * DIM);
    __bf16* kvb  = (__bf16*)take(2ULL * BATCH * KEYS * 2048);
    float*  gout = (float*)take(4ULL * BATCH * LTOT * HID);   // also sp overlay
    __bf16* h2   = (__bf16*)take(2ULL * BATCH * LTOT * HID);  // sp spills here
    __bf16* vt   = (__bf16*)take(2ULL * BATCH * HEADS * DH * KPAD);
    __bf16* wT   = (__bf16*)take(2ULL * 12 * 1024 * 1024);
    float*  pooled = (float*)take(4ULL * BATCH * DIM);
    __bf16* mpin = (__bf16*)take(2ULL * BATCH * DIM);

    // sp[512][68][640] bf16 = 44.6 MB overlays gout(35.7)+h2(17.8): lifetimes
    // disjoint (sp: qk..pv; gout/h2: written after attention completes).
    __bf16* sp = (__bf16*)gout;

    __bf16* wqT   = wT;                    // [1024,1024]
    __bf16* wkvT  = wT + 1 * 1024 * 1024;  // [2048,1024]
    __bf16* woutT = wT + 3 * 1024 * 1024;  // [1024,1024]
    __bf16* f1T   = wT + 4 * 1024 * 1024;  // [4096,1024]
    __bf16* f2T   = wT + 8 * 1024 * 1024;  // [1024,4096]
    __bf16* mpwT  = wT;                    // [4096,1024], used before layers

    // ---- prologue -----------------------------------------------------
    add_pos<<<4096, 256, 0, stream>>>(x, pos_emb, xpos);
    pool_mean<<<128, 256, 0, stream>>>(x, pooled);
    ln_rows<float, false, DIM><<<BATCH, 256, 0, stream>>>(pooled, mpin, mp_ln_g, nullptr);
    transpose_cast<<<dim3(4096 / 32, 1024 / 32), 256, 0, stream>>>(mp_w, mpwT, 1024, 4096);
    launch_gemm(0, mpin, mpwT, lat, mp_b, nullptr, BATCH, 4096, 1024,
                BATCH, 0, LTOT * DIM, 1.f, stream);
    lat_fill<<<2048, 256, 0, stream>>>(latents, lat);

    // ---- layers -------------------------------------------------------
    for (int i = 0; i < 4; ++i) {
        transpose_cast<<<dim3(32, 32), 256, 0, stream>>>(Wq + (size_t)i * 1024 * 1024, wqT, 1024, 1024);
        transpose_cast<<<dim3(64, 32), 256, 0, stream>>>(Wkv + (size_t)i * 1024 * 2048, wkvT, 1024, 2048);
        transpose_cast<<<dim3(32, 32), 256, 0, stream>>>(Wout + (size_t)i * 1024 * 1024, woutT, 1024, 1024);
        transpose_cast<<<dim3(128, 32), 256, 0, stream>>>(ff_w1 + (size_t)i * 1024 * 4096, f1T, 1024, 4096);
        transpose_cast<<<dim3(32, 128), 256, 0, stream>>>(ff_w2 + (size_t)i * 4096 * 1024, f2T, 4096, 1024);

        ln_rows<__bf16, true, DIM><<<BATCH * SEQL, 256, 0, stream>>>(
            xpos, xn, attn_norm_w + i * DIM, attn_norm_b + i * DIM);
        ln_rows<float, true, DIM><<<BATCH * LTOT, 256, 0, stream>>>(
            lat, lnl, attn_lat_w + i * DIM, attn_lat_b + i * DIM);

        // q = (lnl @ Wq) * 0.125  -> bf16
        launch_gemm(2, lnl, wqT, qb, nullptr, nullptr, BATCH * LTOT, 1024, 1024,
                    BATCH * LTOT, 0, 1024, 0.125f, stream);
        // kv rows 0..511 per batch from xn; rows 512..579 from lnl
        launch_gemm(1, xn, wkvT, kvb, nullptr, nullptr, BATCH * SEQL, 2048, 1024,
                    SEQL, (long long)KEYS * 2048, 2048, 1.f, stream);
        launch_gemm(1, lnl, wkvT, kvb + 512 * 2048, nullptr, nullptr, BATCH * LTOT, 2048, 1024,
                    LTOT, (long long)KEYS * 2048, 2048, 1.f, stream);

        // ---- MFMA attention ----
        vt_tr<<<dim3(BATCH * HEADS, KPAD / 32, 2), 256, 0, stream>>>(kvb, vt);
        qk_gemm<<<dim3(BATCH * HEADS, KPAD / 128), 256, 0, stream>>>(qb, kvb, sp);
        softmax_p<<<(BATCH * HEADS * LTOT) / 4, 256, 0, stream>>>(sp);
        pv_gemm<<<BATCH * HEADS, 256, 0, stream>>>(sp, vt, ao);

        launch_gemm(0, ao, woutT, gout, nullptr, nullptr, BATCH * LTOT, 1024, 1024,
                    BATCH * LTOT, 0, 1024, 1.f, stream);
        wout_ln_res<<<BATCH * LTOT, 256, 0, stream>>>(
            gout, lat, ffin, out_ln_w + i * DIM, out_ln_b + i * DIM, ff_ln1_g + i * DIM);

        launch_gemm(3, ffin, f1T, gout, nullptr, nullptr, BATCH * LTOT, HID, 1024,
                    BATCH * LTOT, 0, HID, 1.f, stream);
        ln_rows<float, false, HID><<<BATCH * LTOT, 256, 0, stream>>>(
            gout, h2, ff_ln2_g + i * HID, nullptr);
        launch_gemm(4, h2, f2T, lat, nullptr, lat, BATCH * LTOT, 1024, HID,
                    BATCH * LTOT, 0, 1024, 1.f, stream);
    }
}

// Round 4
// 2267.912 us; speedup vs baseline: 1.6312x; 1.0758x over previous
//
#include <hip/hip_runtime.h>

// ---------------------------------------------------------------------------
// PerceiverResampler forward, MI355X gfx950.
// R4: 256x256 8-phase counted-vmcnt GEMM (T2+T3+T4+T5) for kv/ff1;
//     pow2-shift epilogue (no int div) in 128x128 GEMM; split-K ff2.
// Residual stream (lat) lives in d_out (f32). Workspace ~261 MB.
// ---------------------------------------------------------------------------

typedef __attribute__((ext_vector_type(4))) float f32x4;
typedef __attribute__((ext_vector_type(8))) __bf16 bf16x8;
typedef __attribute__((ext_vector_type(4))) __bf16 bf16x4;

#define BATCH 32
#define SEQL  512
#define DIM   1024
#define HEADS 16
#define DH    64
#define LTOT  68          // 4 mean-pool latents + 64 learned
#define KEYS  580         // SEQL + LTOT
#define KPAD  640         // KEYS padded to 5*128
#define HID   4096
#define LN_EPS 1e-5f

__device__ __forceinline__ float bf2f(__bf16 v) { return (float)v; }
__device__ __forceinline__ __bf16 f2bf(float v) { return (__bf16)v; }

// async 16B global -> LDS (wave-uniform LDS base + lane*16)
__device__ __forceinline__ void gld_lds16(const __bf16* g, __bf16* l) {
    __builtin_amdgcn_global_load_lds(
        (const __attribute__((address_space(1))) void*)g,
        (__attribute__((address_space(3))) void*)l, 16, 0, 0);
}

#define SBAR()   asm volatile("s_barrier" ::: "memory")
#define VMCNT4() asm volatile("s_waitcnt vmcnt(4)" ::: "memory")

// ---------------- block-wide 2-value sum reduction (256 threads) ------------
__device__ __forceinline__ void block_reduce2(float& a, float& b, float* red) {
#pragma unroll
    for (int m = 32; m > 0; m >>= 1) {
        a += __shfl_xor(a, m, 64);
        b += __shfl_xor(b, m, 64);
    }
    int wid = threadIdx.x >> 6, lane = threadIdx.x & 63;
    __syncthreads();
    if (lane == 0) { red[wid] = a; red[4 + wid] = b; }
    __syncthreads();
    a = red[0] + red[1] + red[2] + red[3];
    b = red[4] + red[5] + red[6] + red[7];
}

// ---------------- x_pos = bf16(x + pos_emb) --------------------------------
__global__ __launch_bounds__(256) void add_pos(const float* __restrict__ x,
                                               const float* __restrict__ pos,
                                               __bf16* __restrict__ xp) {
    const int total4 = (BATCH * SEQL * DIM) / 4;
    const int pos4m = (SEQL * DIM) / 4 - 1;
    for (int i = blockIdx.x * 256 + threadIdx.x; i < total4; i += gridDim.x * 256) {
        f32x4 xv = ((const f32x4*)x)[i];
        f32x4 pv = ((const f32x4*)pos)[i & pos4m];
        bf16x4 o;
#pragma unroll
        for (int j = 0; j < 4; ++j) o[j] = f2bf(xv[j] + pv[j]);
        ((bf16x4*)xp)[i] = o;
    }
}

// ---------------- pooled[b][d] = mean_s x[b,s,d] ---------------------------
__global__ __launch_bounds__(256) void pool_mean(const float* __restrict__ x,
                                                 float* __restrict__ pooled) {
    int b = blockIdx.x >> 2;
    int d = ((blockIdx.x & 3) << 8) + threadIdx.x;
    const float* p = x + (size_t)b * SEQL * DIM + d;
    float s = 0.f;
    for (int ss = 0; ss < SEQL; ++ss) s += p[(size_t)ss * DIM];
    pooled[b * DIM + d] = s * (1.f / SEQL);
}

// ---------------- lat rows 4..67 = latents ---------------------------------
__global__ __launch_bounds__(256) void lat_fill(const float* __restrict__ latents,
                                                float* __restrict__ lat) {
    int i = blockIdx.x * 256 + threadIdx.x;
    int b = i >> 14;
    int rem = i & 16383;
    int r = rem >> 8, d4 = rem & 255;
    ((f32x4*)lat)[(size_t)(b * LTOT + 4 + r) * 256 + d4] = ((const f32x4*)latents)[rem];
}

// ---------------- row LayerNorm -> bf16 (vectorized) ------------------------
template <typename Tin, bool STD, int COLS>
__global__ __launch_bounds__(256) void ln_rows(const Tin* __restrict__ in,
                                               __bf16* __restrict__ out,
                                               const float* __restrict__ w,
                                               const float* __restrict__ bb) {
    __shared__ float red[8];
    constexpr int NPT = COLS / 256;
    size_t base = (size_t)blockIdx.x * COLS;
    int t = threadIdx.x;
    int c0 = t * NPT;
    float xv[NPT];
    float s = 0.f, s2 = 0.f;
#pragma unroll
    for (int k4 = 0; k4 < NPT / 4; ++k4) {
        if constexpr (sizeof(Tin) == 2) {
            bf16x4 v = *(const bf16x4*)(in + base + c0 + k4 * 4);
#pragma unroll
            for (int e = 0; e < 4; ++e) {
                float f = bf2f(v[e]);
                xv[k4 * 4 + e] = f; s += f; s2 += f * f;
            }
        } else {
            f32x4 v = *(const f32x4*)((const float*)in + base + c0 + k4 * 4);
#pragma unroll
            for (int e = 0; e < 4; ++e) {
                float f = v[e];
                xv[k4 * 4 + e] = f; s += f; s2 += f * f;
            }
        }
    }
    block_reduce2(s, s2, red);
    float mean = s * (1.f / COLS);
    float var = s2 * (1.f / COLS) - mean * mean;
    float rstd = rsqrtf(var + LN_EPS);
#pragma unroll
    for (int k4 = 0; k4 < NPT / 4; ++k4) {
        f32x4 wv = *(const f32x4*)(w + c0 + k4 * 4);
        f32x4 bv;
        if (STD) bv = *(const f32x4*)(bb + c0 + k4 * 4);
        bf16x4 o;
#pragma unroll
        for (int e = 0; e < 4; ++e) {
            float y = (xv[k4 * 4 + e] - mean) * rstd * wv[e];
            if (STD) y += bv[e];
            o[e] = f2bf(y);
        }
        *(bf16x4*)(out + base + c0 + k4 * 4) = o;
    }
}

// ------- fused: lat = std_ln(gin)*w+b + lat ; ffin = custom_ln(lat)*g1 -----
__global__ __launch_bounds__(256) void wout_ln_res(const float* __restrict__ gin,
                                                   float* __restrict__ lat,
                                                   __bf16* __restrict__ ffin,
                                                   const float* __restrict__ w,
                                                   const float* __restrict__ b,
                                                   const float* __restrict__ g1) {
    __shared__ float red[8];
    size_t base = (size_t)blockIdx.x * DIM;
    int t = threadIdx.x;
    float xv[4];
    float s = 0.f, s2 = 0.f;
#pragma unroll
    for (int k = 0; k < 4; ++k) {
        float v = gin[base + t + (k << 8)];
        xv[k] = v; s += v; s2 += v * v;
    }
    block_reduce2(s, s2, red);
    float mean = s * (1.f / DIM);
    float var = s2 * (1.f / DIM) - mean * mean;
    float rstd = rsqrtf(var + LN_EPS);
    float yv[4];
    s = 0.f; s2 = 0.f;
#pragma unroll
    for (int k = 0; k < 4; ++k) {
        int c = t + (k << 8);
        float y = (xv[k] - mean) * rstd * w[c] + b[c] + lat[base + c];
        yv[k] = y; s += y; s2 += y * y;
        lat[base + c] = y;
    }
    block_reduce2(s, s2, red);
    float mean2 = s * (1.f / DIM);
    float var2 = s2 * (1.f / DIM) - mean2 * mean2;
    float rstd2 = rsqrtf(var2 + LN_EPS);
#pragma unroll
    for (int k = 0; k < 4; ++k) {
        int c = t + (k << 8);
        ffin[base + c] = f2bf((yv[k] - mean2) * rstd2 * g1[c]);
    }
}

// ---------------- transpose + cast: in[K,N] f32 -> out[N,K] bf16 -----------
__global__ __launch_bounds__(256) void transpose_cast(const float* __restrict__ in,
                                                      __bf16* __restrict__ out,
                                                      int K, int N) {
    __shared__ float tile[32][33];
    int n0 = blockIdx.x * 32, k0 = blockIdx.y * 32;
    int tx = threadIdx.x & 31, ty = threadIdx.x >> 5;
#pragma unroll
    for (int p = 0; p < 4; ++p) {
        int kk = ty + p * 8;
        tile[kk][tx] = in[(size_t)(k0 + kk) * N + n0 + tx];
    }
    __syncthreads();
#pragma unroll
    for (int p = 0; p < 4; ++p) {
        int nn = ty + p * 8;
        out[(size_t)(n0 + nn) * K + k0 + tx] = f2bf(tile[tx][nn]);
    }
}

// ---------------- 128x128 MFMA GEMM (m97 structure), pow2 epilogue ---------
// EPI: 0=f32, 1=bf16, 2=bf16*scale, 3=gelu->f32
// POW2: brs = log2(batch_rows); else brs = batch_rows (div path).
template <int EPI, bool POW2>
__global__ __launch_bounds__(256) void gemm_bf16(
    const __bf16* __restrict__ A, const __bf16* __restrict__ Bt,
    void* __restrict__ Cout, const float* __restrict__ bias,
    int M, int N, int K, int lda, int ldb, int brs, long long bstride, int ldc,
    float scale, int az, long long cz) {
    __shared__ __bf16 As[128][64];
    __shared__ __bf16 Bs[128][64];
    const int t = threadIdx.x;
    const int m0 = blockIdx.y * 128, n0 = blockIdx.x * 128;
    A += (size_t)blockIdx.z * az;
    Bt += (size_t)blockIdx.z * az;
    const long long zoff = (long long)blockIdx.z * cz;
    const int wid = t >> 6, lane = t & 63;
    const int wr = wid >> 1, wc = wid & 1;
    const int lrow = lane & 15;
    const int lr = lane >> 3, lc = lane & 7;
    const int src_col = (lc ^ lr) << 3;
    f32x4 acc[4][4] = {};

    int garow[4], gbrow[4];
#pragma unroll
    for (int it = 0; it < 4; ++it) {
        int r = wid * 8 + it * 32 + lr;
        int gm = m0 + r; garow[it] = gm < M ? gm : M - 1;
        int gn = n0 + r; gbrow[it] = gn < N ? gn : N - 1;
    }

    for (int kt = 0; kt < K; kt += 64) {
#pragma unroll
        for (int it = 0; it < 4; ++it) {
            int rb = wid * 8 + it * 32;
            gld_lds16(A + (size_t)garow[it] * lda + kt + src_col, &As[rb][0]);
            gld_lds16(Bt + (size_t)gbrow[it] * ldb + kt + src_col, &Bs[rb][0]);
        }
        __syncthreads();
#pragma unroll
        for (int kc = 0; kc < 2; ++kc) {
            const int ck = (kc << 2) + (lane >> 4);
            bf16x8 af[4], bfr[4];
#pragma unroll
            for (int f = 0; f < 4; ++f) {
                int ra = wr * 64 + f * 16 + lrow;
                af[f] = *(const bf16x8*)(&As[ra][(ck ^ (ra & 7)) << 3]);
                int rb = wc * 64 + f * 16 + lrow;
                bfr[f] = *(const bf16x8*)(&Bs[rb][(ck ^ (rb & 7)) << 3]);
            }
#pragma unroll
            for (int fm = 0; fm < 4; ++fm)
#pragma unroll
                for (int fn = 0; fn < 4; ++fn)
                    acc[fm][fn] = __builtin_amdgcn_mfma_f32_16x16x32_bf16(
                        af[fm], bfr[fn], acc[fm][fn], 0, 0, 0);
        }
        __syncthreads();
    }
    const int rbase = (lane >> 4) << 2;
    const int cofs = lane & 15;
    const int msk = POW2 ? (int)((1u << brs) - 1u) : 0;
#pragma unroll
    for (int fm = 0; fm < 4; ++fm) {
#pragma unroll
        for (int j = 0; j < 4; ++j) {
            int m = m0 + wr * 64 + fm * 16 + rbase + j;
            if (m >= M) continue;
            long long roff;
            if (POW2) roff = (long long)(m >> brs) * bstride + (long long)(m & msk) * ldc;
            else      roff = (long long)(m / brs) * bstride + (long long)(m % brs) * ldc;
            roff += zoff;
#pragma unroll
            for (int fn = 0; fn < 4; ++fn) {
                int n = n0 + wc * 64 + fn * 16 + cofs;
                if (n >= N) continue;
                float v = acc[fm][fn][j];
                if (bias) v += bias[n];
                if (EPI == 0) ((float*)Cout)[roff + n] = v;
                else if (EPI == 1) ((__bf16*)Cout)[roff + n] = f2bf(v);
                else if (EPI == 2) ((__bf16*)Cout)[roff + n] = f2bf(v * scale);
                else ((float*)Cout)[roff + n] =
                    0.5f * v * (1.0f + erff(v * 0.70710678118654752f));
            }
        }
    }
}

// ---------------- 256x256 8-phase counted-vmcnt GEMM (m201 port) -----------
// 512 threads = 8 waves (2M x 4N); wave owns 128x64; BK=64, 2 K-tiles/iter.
// Stage schedule: P1 Blo(t+1) P2 Bhi(t+1) P3 Alo(t+2) P4 Ahi(t+2)
//                 P5 Blo(t+2) P6 Bhi(t+2) P7 Alo(t+3) P8 Ahi(t+3)
// vmcnt(4) at P4/P8 gates the next phase-group's operands (verified hazard-free).
// EPI: 1=bf16 out, 3=gelu f32 out, 0=f32.
template <int EPI>
__global__ __launch_bounds__(512, 2) void gemm256(
    const __bf16* __restrict__ A, const __bf16* __restrict__ Bt,
    void* __restrict__ Cout, const float* __restrict__ bias,
    int M, int N, int K, int brs, long long bstride, int ldc, float scale,
    int gxs) {
    __shared__ __bf16 As[2][256][64];
    __shared__ __bf16 Bs[2][256][64];
    const int t = threadIdx.x;
    const int wid = t >> 6, lane = t & 63;
    const int wr = wid >> 2, wc = wid & 3;
    const int lrow = lane & 15, lk = lane >> 4;
    const int lr8 = lane >> 3;
    const int scol = ((lane & 7) ^ lr8) << 3;

    // XCD-chunked swizzle (bijective since nwg % 8 == 0)
    int nwg = gridDim.x;
    int L = blockIdx.x;
    if ((nwg & 7) == 0) L = (L & 7) * (nwg >> 3) + (L >> 3);
    const int bx = L & ((1 << gxs) - 1), by = L >> gxs;
    const int m0 = by * 256, n0 = bx * 256;

    // per-thread staging source offsets (elements), row-clamped
    unsigned aoff[4], boff[4];
#pragma unroll
    for (int h = 0; h < 2; ++h)
#pragma unroll
        for (int rnd = 0; rnd < 2; ++rnd) {
            int r = h * 128 + rnd * 64 + wid * 8 + lr8;
            int gm = m0 + r; if (gm > M - 1) gm = M - 1;
            aoff[h * 2 + rnd] = (unsigned)(gm * K + scol);
            int gn = n0 + r; if (gn > N - 1) gn = N - 1;
            boff[h * 2 + rnd] = (unsigned)(gn * K + scol);
        }

    auto stgA = [&](int buf, int tile, int h) {
        int kt = tile << 6;
        gld_lds16(A + aoff[h * 2 + 0] + kt, &As[buf][h * 128 + wid * 8][0]);
        gld_lds16(A + aoff[h * 2 + 1] + kt, &As[buf][h * 128 + 64 + wid * 8][0]);
    };
    auto stgB = [&](int buf, int tile, int h) {
        int kt = tile << 6;
        gld_lds16(Bt + boff[h * 2 + 0] + kt, &Bs[buf][h * 128 + wid * 8][0]);
        gld_lds16(Bt + boff[h * 2 + 1] + kt, &Bs[buf][h * 128 + 64 + wid * 8][0]);
    };

    f32x4 acc[8][4] = {};
    bf16x8 AF0[4][2], AF1[4][2], BF[2][2], BF2[2][2];

    auto rdAF = [&](bf16x8 (&AF)[4][2], int buf, int qm) {
#pragma unroll
        for (int i = 0; i < 4; ++i) {
            int ra = wr * 128 + (qm * 4 + i) * 16 + lrow;
            AF[i][0] = *(const bf16x8*)(&As[buf][ra][((lk) ^ (ra & 7)) << 3]);
            AF[i][1] = *(const bf16x8*)(&As[buf][ra][((4 + lk) ^ (ra & 7)) << 3]);
        }
    };
    auto rdBF = [&](bf16x8 (&BV)[2][2], int buf, int qn) {
#pragma unroll
        for (int i = 0; i < 2; ++i) {
            int rb = wc * 64 + (qn * 2 + i) * 16 + lrow;
            BV[i][0] = *(const bf16x8*)(&Bs[buf][rb][((lk) ^ (rb & 7)) << 3]);
            BV[i][1] = *(const bf16x8*)(&Bs[buf][rb][((4 + lk) ^ (rb & 7)) << 3]);
        }
    };
    auto mfq = [&](bf16x8 (&AF)[4][2], bf16x8 (&BV)[2][2], int mo, int no) {
        __builtin_amdgcn_s_setprio(1);
#pragma unroll
        for (int i = 0; i < 4; ++i)
#pragma unroll
            for (int nf = 0; nf < 2; ++nf)
#pragma unroll
                for (int ks = 0; ks < 2; ++ks)
                    acc[mo + i][no + nf] = __builtin_amdgcn_mfma_f32_16x16x32_bf16(
                        AF[i][ks], BV[nf][ks], acc[mo + i][no + nf], 0, 0, 0);
        __builtin_amdgcn_s_setprio(0);
    };

    const int nt = K >> 6;           // even for all users (K=1024)
    // prologue: stages matching steady-state P3..P8 of "iteration -1"
    stgA(0, 0, 0); stgA(0, 0, 1);
    stgB(0, 0, 0); stgB(0, 0, 1);
    stgA(1, 1, 0); stgA(1, 1, 1);
    VMCNT4();                        // tile0 fully resident; A(1) in flight
    SBAR();

    for (int tt = 0; tt < nt; tt += 2) {
        const int t1 = tt + 1;
        const int t2 = (tt + 2 < nt) ? tt + 2 : nt - 1;
        const int t3 = (tt + 3 < nt) ? tt + 3 : nt - 1;
        // P1
        rdAF(AF0, 0, 0); rdBF(BF, 0, 0);
        stgB(1, t1, 0);
        SBAR();
        mfq(AF0, BF, 0, 0);
        SBAR();
        // P2
        rdAF(AF1, 0, 1);
        stgB(1, t1, 1);
        SBAR();
        mfq(AF1, BF, 4, 0);
        SBAR();
        // P3
        rdBF(BF2, 0, 1);
        stgA(0, t2, 0);
        SBAR();
        mfq(AF1, BF2, 4, 2);
        SBAR();
        // P4
        stgA(0, t2, 1);
        SBAR();
        mfq(AF0, BF2, 0, 2);
        VMCNT4();
        SBAR();
        // P5
        rdAF(AF0, 1, 0); rdBF(BF, 1, 0);
        stgB(0, t2, 0);
        SBAR();
        mfq(AF0, BF, 0, 0);
        SBAR();
        // P6
        rdAF(AF1, 1, 1);
        stgB(0, t2, 1);
        SBAR();
        mfq(AF1, BF, 4, 0);
        SBAR();
        // P7
        rdBF(BF2, 1, 1);
        stgA(1, t3, 0);
        SBAR();
        mfq(AF1, BF2, 4, 2);
        SBAR();
        // P8
        stgA(1, t3, 1);
        SBAR();
        mfq(AF0, BF2, 0, 2);
        VMCNT4();
        SBAR();
    }

    const int rbase = (lane >> 4) << 2;
    const int cofs = lane & 15;
    const int msk = (int)((1u << brs) - 1u);
#pragma unroll
    for (int mf = 0; mf < 8; ++mf) {
#pragma unroll
        for (int j = 0; j < 4; ++j) {
            int m = m0 + wr * 128 + mf * 16 + rbase + j;
            if (m >= M) continue;
            long long roff = (long long)(m >> brs) * bstride +
                             (long long)(m & msk) * ldc;
#pragma unroll
            for (int nf = 0; nf < 4; ++nf) {
                int n = n0 + wc * 64 + nf * 16 + cofs;
                if (n >= N) continue;
                float v = acc[mf][nf][j];
                if (bias) v += bias[n];
                if (EPI == 1) ((__bf16*)Cout)[roff + n] = f2bf(v);
                else if (EPI == 3) ((float*)Cout)[roff + n] =
                    0.5f * v * (1.0f + erff(v * 0.70710678118654752f));
                else ((float*)Cout)[roff + n] = v;
            }
        }
    }
}

// ---------------- split-K reduce: lat += p0+p1+p2+p3 -----------------------
__global__ __launch_bounds__(256) void splitk_add(const float* __restrict__ p,
                                                  float* __restrict__ lat) {
    const int S = (2176 * 1024) / 4;
    int i = blockIdx.x * 256 + threadIdx.x;
    f32x4 a = ((const f32x4*)p)[i];
    f32x4 b = ((const f32x4*)p)[i + S];
    f32x4 c = ((const f32x4*)p)[i + 2 * S];
    f32x4 d = ((const f32x4*)p)[i + 3 * S];
    f32x4 l = ((f32x4*)lat)[i];
    l = l + a + b + c + d;
    ((f32x4*)lat)[i] = l;
}

// ---------------- attention: S = Q @ K^T (MFMA) ----------------------------
__global__ __launch_bounds__(256) void qk_gemm(const __bf16* __restrict__ q,
                                               const __bf16* __restrict__ kv,
                                               __bf16* __restrict__ sp) {
    __shared__ __bf16 Qs[80][64];
    __shared__ __bf16 Ks[128][64];
    const int bh = blockIdx.x, b = bh >> 4, h = bh & 15;
    const int n0 = blockIdx.y * 128;
    const int t = threadIdx.x, wid = t >> 6, lane = t & 63;
    const __bf16* qbase = q + (size_t)b * LTOT * DIM + h * DH;
    const __bf16* kbase = kv + (size_t)b * KEYS * 2048 + h * DH;
    const bf16x8 zero8 = {};

    for (int s = t; s < 80 * 8; s += 256) {
        int r = s >> 3, c8 = s & 7;
        bf16x8 v = zero8;
        if (r < LTOT) v = *(const bf16x8*)(qbase + (size_t)r * DIM + (c8 << 3));
        *(bf16x8*)(&Qs[r][(c8 ^ (r & 7)) << 3]) = v;
    }
    for (int s = t; s < 128 * 8; s += 256) {
        int r = s >> 3, c8 = s & 7;
        int gk = n0 + r; if (gk >= KEYS) gk = KEYS - 1;
        bf16x8 v = *(const bf16x8*)(kbase + (size_t)gk * 2048 + (c8 << 3));
        *(bf16x8*)(&Ks[r][(c8 ^ (r & 7)) << 3]) = v;
    }
    __syncthreads();

    const int lrow = lane & 15;
    f32x4 acc[5][2] = {};
#pragma unroll
    for (int kc = 0; kc < 2; ++kc) {
        const int ck = (kc << 2) + (lane >> 4);
        bf16x8 bfr[2];
#pragma unroll
        for (int fn = 0; fn < 2; ++fn) {
            int rb = wid * 32 + fn * 16 + lrow;
            bfr[fn] = *(const bf16x8*)(&Ks[rb][(ck ^ (rb & 7)) << 3]);
        }
#pragma unroll
        for (int fm = 0; fm < 5; ++fm) {
            int ra = fm * 16 + lrow;
            bf16x8 af = *(const bf16x8*)(&Qs[ra][(ck ^ (ra & 7)) << 3]);
#pragma unroll
            for (int fn = 0; fn < 2; ++fn)
                acc[fm][fn] = __builtin_amdgcn_mfma_f32_16x16x32_bf16(
                    af, bfr[fn], acc[fm][fn], 0, 0, 0);
        }
    }
    __bf16* srow = sp + (size_t)bh * LTOT * KPAD;
    const int rbase = (lane >> 4) << 2, cofs = lane & 15;
#pragma unroll
    for (int fm = 0; fm < 5; ++fm)
#pragma unroll
        for (int j = 0; j < 4; ++j) {
            int r = fm * 16 + rbase + j;
            if (r >= LTOT) continue;
#pragma unroll
            for (int fn = 0; fn < 2; ++fn) {
                int col = n0 + wid * 32 + fn * 16 + cofs;
                srow[(size_t)r * KPAD + col] = f2bf(acc[fm][fn][j]);
            }
        }
}

// ---------------- row softmax in place, writes P/l, zeros for pad ----------
__global__ __launch_bounds__(256) void softmax_p(__bf16* __restrict__ sp) {
    const int row = blockIdx.x * 4 + (threadIdx.x >> 6);
    const int lane = threadIdx.x & 63;
    __bf16* p = sp + (size_t)row * KPAD;
    float v[10];
    float m = -3.0e38f;
#pragma unroll
    for (int i = 0; i < 10; ++i) {
        int c = (i << 6) + lane;
        float f = (c < KEYS) ? bf2f(p[c]) : -3.0e38f;
        v[i] = f; m = fmaxf(m, f);
    }
#pragma unroll
    for (int mk = 32; mk > 0; mk >>= 1) m = fmaxf(m, __shfl_xor(m, mk, 64));
    float l = 0.f;
#pragma unroll
    for (int i = 0; i < 10; ++i) {
        int c = (i << 6) + lane;
        float e = (c < KEYS) ? __expf(v[i] - m) : 0.f;
        v[i] = e; l += e;
    }
#pragma unroll
    for (int mk = 32; mk > 0; mk >>= 1) l += __shfl_xor(l, mk, 64);
    float inv = 1.f / l;
#pragma unroll
    for (int i = 0; i < 10; ++i) {
        int c = (i << 6) + lane;
        p[c] = f2bf(v[i] * inv);
    }
}

// ---------------- vt[bh][d][k] = v[b][k][h*64+d] ---------------------------
__global__ __launch_bounds__(256) void vt_tr(const __bf16* __restrict__ kv,
                                             __bf16* __restrict__ vt) {
    __shared__ __bf16 tile[32][34];
    const int bh = blockIdx.x, b = bh >> 4, h = bh & 15;
    const int k0 = blockIdx.y * 32, d0 = blockIdx.z * 32;
    const int tx = threadIdx.x & 31, ty = threadIdx.x >> 5;
    const __bf16* vbase = kv + (size_t)b * KEYS * 2048 + 1024 + h * DH;
#pragma unroll
    for (int p = 0; p < 4; ++p) {
        int kk = k0 + ty + p * 8;
        int kc = kk < KEYS ? kk : KEYS - 1;
        tile[ty + p * 8][tx] = vbase[(size_t)kc * 2048 + d0 + tx];
    }
    __syncthreads();
    __bf16* obase = vt + (size_t)bh * DH * KPAD;
#pragma unroll
    for (int p = 0; p < 4; ++p) {
        int nn = ty + p * 8;
        __bf16 val = (k0 + tx < KEYS) ? tile[tx][nn] : (__bf16)0.f;
        obase[(size_t)(d0 + nn) * KPAD + k0 + tx] = val;
    }
}

// ---------------- O = P @ V (MFMA), grid 512 bh ----------------------------
__global__ __launch_bounds__(256) void pv_gemm(const __bf16* __restrict__ sp,
                                               const __bf16* __restrict__ vt,
                                               __bf16* __restrict__ ao) {
    __shared__ __bf16 Ps[80][64];
    __shared__ __bf16 Vs[64][64];
    const int bh = blockIdx.x, b = bh >> 4, h = bh & 15;
    const int t = threadIdx.x, wid = t >> 6, lane = t & 63;
    const int lrow = lane & 15;
    const __bf16* pbase = sp + (size_t)bh * LTOT * KPAD;
    const __bf16* vbase = vt + (size_t)bh * DH * KPAD;
    const bf16x8 zero8 = {};
    f32x4 acc[5] = {};

    for (int kt = 0; kt < KPAD; kt += 64) {
        for (int s = t; s < 80 * 8; s += 256) {
            int r = s >> 3, c8 = s & 7;
            bf16x8 v = zero8;
            if (r < LTOT) v = *(const bf16x8*)(pbase + (size_t)r * KPAD + kt + (c8 << 3));
            *(bf16x8*)(&Ps[r][(c8 ^ (r & 7)) << 3]) = v;
        }
        for (int s = t; s < 64 * 8; s += 256) {
            int r = s >> 3, c8 = s & 7;
            bf16x8 v = *(const bf16x8*)(vbase + (size_t)r * KPAD + kt + (c8 << 3));
            *(bf16x8*)(&Vs[r][(c8 ^ (r & 7)) << 3]) = v;
        }
        __syncthreads();
#pragma unroll
        for (int kc = 0; kc < 2; ++kc) {
            const int ck = (kc << 2) + (lane >> 4);
            int rb = wid * 16 + lrow;
            bf16x8 bfr = *(const bf16x8*)(&Vs[rb][(ck ^ (rb & 7)) << 3]);
#pragma unroll
            for (int fm = 0; fm < 5; ++fm) {
                int ra = fm * 16 + lrow;
                bf16x8 af = *(const bf16x8*)(&Ps[ra][(ck ^ (ra & 7)) << 3]);
                acc[fm] = __builtin_amdgcn_mfma_f32_16x16x32_bf16(
                    af, bfr, acc[fm], 0, 0, 0);
            }
        }
        __syncthreads();
    }
    __bf16* obase = ao + (size_t)b * LTOT * DIM + h * DH;
    const int rbase = (lane >> 4) << 2, cofs = lane & 15;
#pragma unroll
    for (int fm = 0; fm < 5; ++fm)
#pragma unroll
        for (int j = 0; j < 4; ++j) {
            int r = fm * 16 + rbase + j;
            if (r >= LTOT) continue;
            obase[(size_t)r * DIM + wid * 16 + cofs] = f2bf(acc[fm][j]);
        }
}

// ---------------------------------------------------------------------------
template <int EPI, bool POW2>
static void g128(const __bf16* A, const __bf16* Bt, void* C, const float* bias,
                 int M, int N, int K, int lda, int ldb, int brs, long long bs,
                 int ldc, float scale, int gz, int az, long long cz,
                 hipStream_t s) {
    dim3 g(N / 128, (M + 127) / 128, gz);
    gemm_bf16<EPI, POW2><<<g, 256, 0, s>>>(A, Bt, C, bias, M, N, K, lda, ldb,
                                           brs, bs, ldc, scale, az, cz);
}

extern "C" void kernel_launch(void* const* d_in, const int* in_sizes, int n_in,
                              void* d_out, int out_size, void* d_ws, size_t ws_size,
                              hipStream_t stream) {
    (void)in_sizes; (void)n_in; (void)out_size; (void)ws_size;
    const float* x          = (const float*)d_in[0];
    const float* pos_emb    = (const float*)d_in[2];
    const float* latents    = (const float*)d_in[3];
    const float* mp_ln_g    = (const float*)d_in[4];
    const float* mp_w       = (const float*)d_in[5];
    const float* mp_b       = (const float*)d_in[6];
    const float* attn_norm_w= (const float*)d_in[7];
    const float* attn_norm_b= (const float*)d_in[8];
    const float* attn_lat_w = (const float*)d_in[9];
    const float* attn_lat_b = (const float*)d_in[10];
    const float* Wq         = (const float*)d_in[11];
    const float* Wkv        = (const float*)d_in[12];
    const float* Wout       = (const float*)d_in[13];
    const float* out_ln_w   = (const float*)d_in[14];
    const float* out_ln_b   = (const float*)d_in[15];
    const float* ff_ln1_g   = (const float*)d_in[16];
    const float* ff_w1      = (const float*)d_in[17];
    const float* ff_ln2_g   = (const float*)d_in[18];
    const float* ff_w2      = (const float*)d_in[19];

    float* lat = (float*)d_out;                    // residual stream, f32

    char* ws = (char*)d_ws;
    size_t off = 0;
    auto take = [&](size_t bytes) -> char* {
        char* p = ws + off;
        off += (bytes + 255) & ~(size_t)255;
        return p;
    };
    __bf16* xpos = (__bf16*)take(2ULL * BATCH * SEQL * DIM);
    __bf16* xn   = (__bf16*)take(2ULL * BATCH * SEQL * DIM);
    __bf16* lnl  = (__bf16*)take(2ULL * BATCH * LTOT * DIM);
    __bf16* ffin = (__bf16*)take(2ULL * BATCH * LTOT * DIM);
    __bf16* qb   = (__bf16*)take(2ULL * BATCH * LTOT * DIM);
    __bf16* ao   = (__bf16*)take(2ULL * BATCH * LTOT * DIM);
    __bf16* kvb  = (__bf16*)take(2ULL * BATCH * KEYS * 2048);
    float*  gout = (float*)take(4ULL * BATCH * LTOT * HID);   // sp / ff2-partials overlay
    __bf16* h2   = (__bf16*)take(2ULL * BATCH * LTOT * HID);  // sp spills here
    __bf16* vt   = (__bf16*)take(2ULL * BATCH * HEADS * DH * KPAD);
    __bf16* wT   = (__bf16*)take(2ULL * 12 * 1024 * 1024);
    float*  pooled = (float*)take(4ULL * BATCH * DIM);
    __bf16* mpin = (__bf16*)take(2ULL * BATCH * DIM);

    __bf16* sp = (__bf16*)gout;            // 44.6 MB, disjoint lifetime

    __bf16* wqT   = wT;                    // [1024,1024]
    __bf16* wkvT  = wT + 1 * 1024 * 1024;  // [2048,1024]
    __bf16* woutT = wT + 3 * 1024 * 1024;  // [1024,1024]
    __bf16* f1T   = wT + 4 * 1024 * 1024;  // [4096,1024]
    __bf16* f2T   = wT + 8 * 1024 * 1024;  // [1024,4096]
    __bf16* mpwT  = wT;                    // [4096,1024], used before layers

    // ---- prologue -----------------------------------------------------
    add_pos<<<4096, 256, 0, stream>>>(x, pos_emb, xpos);
    pool_mean<<<128, 256, 0, stream>>>(x, pooled);
    ln_rows<float, false, DIM><<<BATCH, 256, 0, stream>>>(pooled, mpin, mp_ln_g, nullptr);
    transpose_cast<<<dim3(128, 32), 256, 0, stream>>>(mp_w, mpwT, 1024, 4096);
    g128<0, true>(mpin, mpwT, lat, mp_b, BATCH, 4096, 1024, 1024, 1024,
                  5, 0, LTOT * DIM, 1.f, 1, 0, 0, stream);
    lat_fill<<<2048, 256, 0, stream>>>(latents, lat);

    // ---- layers -------------------------------------------------------
    for (int i = 0; i < 4; ++i) {
        transpose_cast<<<dim3(32, 32), 256, 0, stream>>>(Wq + (size_t)i * 1024 * 1024, wqT, 1024, 1024);
        transpose_cast<<<dim3(64, 32), 256, 0, stream>>>(Wkv + (size_t)i * 1024 * 2048, wkvT, 1024, 2048);
        transpose_cast<<<dim3(32, 32), 256, 0, stream>>>(Wout + (size_t)i * 1024 * 1024, woutT, 1024, 1024);
        transpose_cast<<<dim3(128, 32), 256, 0, stream>>>(ff_w1 + (size_t)i * 1024 * 4096, f1T, 1024, 4096);
        transpose_cast<<<dim3(32, 128), 256, 0, stream>>>(ff_w2 + (size_t)i * 4096 * 1024, f2T, 4096, 1024);

        ln_rows<__bf16, true, DIM><<<BATCH * SEQL, 256, 0, stream>>>(
            xpos, xn, attn_norm_w + i * DIM, attn_norm_b + i * DIM);
        ln_rows<float, true, DIM><<<BATCH * LTOT, 256, 0, stream>>>(
            lat, lnl, attn_lat_w + i * DIM, attn_lat_b + i * DIM);

        // q = (lnl @ Wq) * 0.125 -> bf16
        g128<2, true>(lnl, wqT, qb, nullptr, BATCH * LTOT, 1024, 1024, 1024, 1024,
                      31, 0, 1024, 0.125f, 1, 0, 0, stream);
        // kv rows 0..511 per batch from xn (256x256 8-phase kernel)
        gemm256<1><<<dim3(512), 512, 0, stream>>>(
            xn, wkvT, kvb, nullptr, BATCH * SEQL, 2048, 1024,
            9, (long long)KEYS * 2048, 2048, 1.f, 3);
        // kv rows 512..579 per batch from lnl
        g128<1, false>(lnl, wkvT, kvb + 512 * 2048, nullptr, BATCH * LTOT, 2048, 1024,
                       1024, 1024, LTOT, (long long)KEYS * 2048, 2048, 1.f, 1, 0, 0, stream);

        // ---- MFMA attention ----
        vt_tr<<<dim3(BATCH * HEADS, KPAD / 32, 2), 256, 0, stream>>>(kvb, vt);
        qk_gemm<<<dim3(BATCH * HEADS, KPAD / 128), 256, 0, stream>>>(qb, kvb, sp);
        softmax_p<<<(BATCH * HEADS * LTOT) / 4, 256, 0, stream>>>(sp);
        pv_gemm<<<BATCH * HEADS, 256, 0, stream>>>(sp, vt, ao);

        g128<0, true>(ao, woutT, gout, nullptr, BATCH * LTOT, 1024, 1024, 1024, 1024,
                      31, 0, 1024, 1.f, 1, 0, 0, stream);
        wout_ln_res<<<BATCH * LTOT, 256, 0, stream>>>(
            gout, lat, ffin, out_ln_w + i * DIM, out_ln_b + i * DIM, ff_ln1_g + i * DIM);

        // ff1 (gelu) on 256x256 kernel
        gemm256<3><<<dim3(144), 512, 0, stream>>>(
            ffin, f1T, gout, nullptr, BATCH * LTOT, HID, 1024,
            31, 0, HID, 1.f, 4);
        ln_rows<float, false, HID><<<BATCH * LTOT, 256, 0, stream>>>(
            gout, h2, ff_ln2_g + i * HID, nullptr);
        // ff2 split-K x4 -> partials in gout, then reduce into lat
        g128<0, true>(h2, f2T, gout, nullptr, BATCH * LTOT, 1024, 1024, HID, HID,
                      31, 0, 1024, 1.f, 4, 1024, 2176LL * 1024, stream);
        splitk_add<<<2176, 256, 0, stream>>>(gout, lat);
    }
}